// Round 3
// baseline (437.950 us; speedup 1.0000x reference)
//
#include <hip/hip_runtime.h>
#include <hip/hip_bf16.h>
#include <cstdint>

// Problem constants
#define BB 2
#define SS 2048
#define DD 1024
#define HH 16
#define HDIM 64
#define MROWS (BB*SS)   // 4096

typedef __bf16 bf16;
using bf16x8 = __bf16 __attribute__((ext_vector_type(8)));
using bf16x4 = __bf16 __attribute__((ext_vector_type(4)));
using bf16x2 = __bf16 __attribute__((ext_vector_type(2)));
using f32x4  = float __attribute__((ext_vector_type(4)));

__device__ __forceinline__ float gelu_exact(float x) {
    return 0.5f * x * (1.f + erff(x * 0.70710678118654752f));
}

// global->LDS direct DMA, 16B per lane (lane i deposits at base + i*16).
__device__ __forceinline__ void stage16(const bf16* g, bf16* lds_chunk_base, int lane) {
#if __has_builtin(__builtin_amdgcn_global_load_lds)
    __builtin_amdgcn_global_load_lds((const __attribute__((address_space(1))) void*)g,
                                     (__attribute__((address_space(3))) void*)lds_chunk_base,
                                     16, 0, 0);
#else
    *(bf16x8*)(lds_chunk_base + lane * 8) = *(const bf16x8*)g;
#endif
}

// ---------------- fused prep: cast x, pack mask, transpose all weights ----------------
// block ranges: [0,4096) cast x | [4096,20480) pack mask | [20480,32768) transposes
__global__ __launch_bounds__(256) void prep_kernel(
    const float* __restrict__ x, bf16* __restrict__ x_b,
    const int* __restrict__ mask, unsigned long long* __restrict__ maskb,
    const float* __restrict__ Wq, const float* __restrict__ Wk,
    const float* __restrict__ Wv, const float* __restrict__ Wo,
    const float* __restrict__ W1, const float* __restrict__ W2,
    bf16* __restrict__ Wqkv_t, bf16* __restrict__ Wo_t,
    bf16* __restrict__ W1_t, bf16* __restrict__ W2_t) {
    const int bid = blockIdx.x;
    if (bid < 4096) {
        int i = bid * 256 + threadIdx.x;
        float4 v = ((const float4*)x)[i];
        bf16x4 o;
        o[0] = (bf16)v.x; o[1] = (bf16)v.y; o[2] = (bf16)v.z; o[3] = (bf16)v.w;
        *(bf16x4*)(x_b + (size_t)i * 4) = o;
        return;
    }
    if (bid < 20480) {
        int gid = (bid - 4096) * 256 + threadIdx.x;
        int mv = mask[gid];
        unsigned long long bal = __ballot(mv == 1);
        if ((threadIdx.x & 63) == 0) maskb[gid >> 6] = bal;
        return;
    }
    int t = bid - 20480;
    const float* W; bf16* Wt; int K, N, bx, by;
    if (t < 4096) {
        int wsel = t >> 10;
        int tt = t & 1023;
        W  = (wsel == 0) ? Wq : (wsel == 1) ? Wk : (wsel == 2) ? Wv : Wo;
        Wt = (wsel == 3) ? Wo_t : (Wqkv_t + (size_t)wsel * 1024 * 1024);
        K = 1024; N = 1024; bx = (tt & 31) * 32; by = (tt >> 5) * 32;
    } else if (t < 8192) {
        int tt = t - 4096;
        W = W1; Wt = W1_t; K = 1024; N = 4096;
        bx = (tt & 127) * 32; by = (tt >> 7) * 32;
    } else {
        int tt = t - 8192;
        W = W2; Wt = W2_t; K = 4096; N = 1024;
        bx = (tt & 31) * 32; by = (tt >> 5) * 32;
    }
    __shared__ float tile[32][33];
    int tx = threadIdx.x & 31;
    int ty = threadIdx.x >> 5;
#pragma unroll
    for (int j = 0; j < 4; ++j)
        tile[ty + j * 8][tx] = W[(size_t)(by + ty + j * 8) * N + bx + tx];
    __syncthreads();
#pragma unroll
    for (int j = 0; j < 4; ++j)
        Wt[(size_t)(bx + ty + j * 8) * K + by + tx] = (bf16)tile[tx][ty + j * 8];
}

// ---------------- bf16 MFMA GEMM: C = A(M x ldk) * Bt(N x ldk)^T, 128x128 tile ----------------
// Used only for O-proj (shape too small for the 256x256 template).
// EPI: 4 = raw fp32 partial to (z ? C2 : C).
template <int EPI>
__global__ __launch_bounds__(256, 3) void gemm_bt(const bf16* __restrict__ A,
                                                  const bf16* __restrict__ Bt,
                                                  void* __restrict__ C,
                                                  void* __restrict__ C2,
                                                  const float* __restrict__ bias,
                                                  int M, int N, int K, int ldk) {
    __shared__ __align__(16) bf16 As[128 * 64];
    __shared__ __align__(16) bf16 Bs[128 * 64];
    const int tid  = threadIdx.x;
    const int lane = tid & 63;
    const int wave = tid >> 6;
    const int l16  = lane & 15;
    const int quad = lane >> 4;
    const int wm = wave >> 1, wn = wave & 1;
    const int m0 = blockIdx.y * 128, n0 = blockIdx.x * 128;
    const int z  = blockIdx.z;
    A  += (size_t)z * K;
    Bt += (size_t)z * K;

    f32x4 acc[4][4];
#pragma unroll
    for (int i = 0; i < 4; ++i)
#pragma unroll
        for (int j = 0; j < 4; ++j) acc[i][j] = (f32x4){0.f, 0.f, 0.f, 0.f};

    const int nsteps = K >> 6;
    for (int kt = 0; kt < nsteps; ++kt) {
        const int kbase = kt << 6;
#pragma unroll
        for (int c = 0; c < 4; ++c) {
            int chunk = wave * 4 + c;
            int gi = chunk * 64 + lane;
            int m  = gi >> 3;
            int cp = gi & 7;
            int g  = cp ^ (m & 7);
            stage16(A  + (size_t)(m0 + m) * ldk + kbase + g * 8, As + chunk * 512, lane);
            stage16(Bt + (size_t)(n0 + m) * ldk + kbase + g * 8, Bs + chunk * 512, lane);
        }
        __syncthreads();
#pragma unroll
        for (int ks = 0; ks < 2; ++ks) {
            bf16x8 af[4], bfr[4];
#pragma unroll
            for (int i = 0; i < 4; ++i) {
                int m = wm * 64 + i * 16 + l16;
                int g = ks * 4 + quad;
                af[i]  = *(const bf16x8*)(As + m * 64 + ((g ^ (m & 7)) * 8));
                int n = wn * 64 + i * 16 + l16;
                bfr[i] = *(const bf16x8*)(Bs + n * 64 + ((g ^ (n & 7)) * 8));
            }
#pragma unroll
            for (int i = 0; i < 4; ++i)
#pragma unroll
                for (int j = 0; j < 4; ++j)
                    acc[i][j] = __builtin_amdgcn_mfma_f32_16x16x32_bf16(af[i], bfr[j], acc[i][j], 0, 0, 0);
        }
        __syncthreads();
    }

    float* Cz = (EPI == 4) ? (z ? (float*)C2 : (float*)C) : nullptr;
#pragma unroll
    for (int i = 0; i < 4; ++i) {
        int row = m0 + wm * 64 + i * 16 + quad * 4;
#pragma unroll
        for (int j = 0; j < 4; ++j) {
            int col = n0 + wn * 64 + j * 16 + l16;
            float bv = (EPI == 2) ? bias[col] : 0.f;
#pragma unroll
            for (int r = 0; r < 4; ++r) {
                float v = acc[i][j][r];
                if (EPI == 2) v = gelu_exact(v + bv);
                size_t idx = (size_t)(row + r) * N + col;
                if (EPI == 4) Cz[idx] = v;
                else          ((bf16*)C)[idx] = (bf16)v;
            }
        }
    }
}

// ---------------- 256x256 8-wave 4-phase counted-vmcnt GEMM (T2+T3+T4+T5 port) ----------------
// C = A(M x ldk) * Bt(N x ldk)^T. BK=64, 512 threads (2x4 waves), per-wave C = 128x64.
// LDS 128 KiB: double-buffered A[256x64] + B[256x64], XOR-granule swizzle, staged via
// global_load_lds with pre-swizzled source (rule #21: both-sides-or-neither).
// Schedule per K-tile t (buf p = t&1):
//   P1: ds_read A-half0(8xb128) + B-half0(4xb128); bar; MFMA quad(0,0); bar
//   P2: ds_read B-half1(4xb128);                   bar; MFMA quad(0,1); bar
//   P3: ds_read A-half1(8xb128);                   bar; MFMA quad(1,1); bar
//   P4: stage tile t+2 into buf p (safe: all reads of p done at P3 end-barrier);
//       bar; MFMA quad(1,0); s_waitcnt vmcnt(8) (waits t+1's loads only, issued a
//       full tile ago; leaves t+2's 8 in flight across the barrier); bar
// EPI: 0 = bf16 raw; 2 = +bias,gelu bf16; 4 = fp32 partial to C[z].
template <int EPI>
__global__ __launch_bounds__(512, 2) void gemm256(const bf16* __restrict__ A,
                                                  const bf16* __restrict__ Bt,
                                                  void* __restrict__ C0, void* __restrict__ C1,
                                                  void* __restrict__ C2v, void* __restrict__ C3,
                                                  const float* __restrict__ bias,
                                                  int M, int N, int K, int ldk) {
    __shared__ __align__(16) bf16 As[2 * 256 * 64];   // 64 KiB
    __shared__ __align__(16) bf16 Bs[2 * 256 * 64];   // 64 KiB
    const int tid  = threadIdx.x;
    const int lane = tid & 63;
    const int wave = tid >> 6;     // 0..7
    const int l16  = lane & 15;
    const int quad = lane >> 4;
    const int wm = wave >> 2;      // 0..1
    const int wn = wave & 3;       // 0..3
    const int m0 = blockIdx.y * 256, n0 = blockIdx.x * 256;
    const int z  = blockIdx.z;
    A  += (size_t)z * K;
    Bt += (size_t)z * K;

    // staging geometry: 4 A-chunks + 4 B-chunks per wave; chunk c covers rows
    // wave*32+c*8 .. +7; lane l -> row +(l>>3), stored granule l&7, source granule
    // (l&7)^(row&7)  => LDS[row][g^(row&7)] = global[row][g].
    const int rl = lane >> 3;
    const int cpn = lane & 7;
    const bf16* pA[4]; const bf16* pB[4];
    int ldsoff[4];
#pragma unroll
    for (int c = 0; c < 4; ++c) {
        int row = wave * 32 + c * 8 + rl;
        int g = cpn ^ (row & 7);
        pA[c] = A + (size_t)(m0 + row) * ldk + g * 8;
        pB[c] = Bt + (size_t)(n0 + row) * ldk + g * 8;
        ldsoff[c] = (wave * 4 + c) * 512;
    }

    f32x4 acc[8][4];
#pragma unroll
    for (int i = 0; i < 8; ++i)
#pragma unroll
        for (int j = 0; j < 4; ++j) acc[i][j] = (f32x4){0.f, 0.f, 0.f, 0.f};

    const int nt = K >> 6;

    auto stage_tile = [&](int t) {
        const int kb = t << 6;
        bf16* dstA = As + (t & 1) * 16384;
        bf16* dstB = Bs + (t & 1) * 16384;
#pragma unroll
        for (int c = 0; c < 4; ++c) stage16(pA[c] + kb, dstA + ldsoff[c], lane);
#pragma unroll
        for (int c = 0; c < 4; ++c) stage16(pB[c] + kb, dstB + ldsoff[c], lane);
    };

    // prologue: tiles 0 and 1 in flight; wait tile 0 only (8 newest stay in flight)
    stage_tile(0);
    stage_tile(1);
    asm volatile("s_waitcnt vmcnt(8)" ::: "memory");
    __builtin_amdgcn_s_barrier();

    for (int t = 0; t < nt; ++t) {
        const bf16* AsP = As + (t & 1) * 16384;
        const bf16* BsP = Bs + (t & 1) * 16384;
        bf16x8 af[4][2], b0[2][2], b1[2][2];

        // ---- P1: A half 0 + B half 0 ; MFMA quad (mh0, nh0) ----
#pragma unroll
        for (int i = 0; i < 4; ++i) {
            int row = wm * 128 + i * 16 + l16;
#pragma unroll
            for (int kk = 0; kk < 2; ++kk)
                af[i][kk] = *(const bf16x8*)(AsP + row * 64 + (((kk * 4 + quad) ^ (row & 7)) * 8));
        }
#pragma unroll
        for (int j = 0; j < 2; ++j) {
            int row = wn * 64 + j * 16 + l16;
#pragma unroll
            for (int kk = 0; kk < 2; ++kk)
                b0[j][kk] = *(const bf16x8*)(BsP + row * 64 + (((kk * 4 + quad) ^ (row & 7)) * 8));
        }
        __builtin_amdgcn_s_barrier();
        __builtin_amdgcn_s_setprio(1);
#pragma unroll
        for (int i = 0; i < 4; ++i)
#pragma unroll
            for (int j = 0; j < 2; ++j)
#pragma unroll
                for (int kk = 0; kk < 2; ++kk)
                    acc[i][j] = __builtin_amdgcn_mfma_f32_16x16x32_bf16(af[i][kk], b0[j][kk], acc[i][j], 0, 0, 0);
        __builtin_amdgcn_s_setprio(0);
        __builtin_amdgcn_s_barrier();

        // ---- P2: B half 1 ; MFMA quad (mh0, nh1) ----
#pragma unroll
        for (int j = 0; j < 2; ++j) {
            int row = wn * 64 + (j + 2) * 16 + l16;
#pragma unroll
            for (int kk = 0; kk < 2; ++kk)
                b1[j][kk] = *(const bf16x8*)(BsP + row * 64 + (((kk * 4 + quad) ^ (row & 7)) * 8));
        }
        __builtin_amdgcn_s_barrier();
        __builtin_amdgcn_s_setprio(1);
#pragma unroll
        for (int i = 0; i < 4; ++i)
#pragma unroll
            for (int j = 0; j < 2; ++j)
#pragma unroll
                for (int kk = 0; kk < 2; ++kk)
                    acc[i][j + 2] = __builtin_amdgcn_mfma_f32_16x16x32_bf16(af[i][kk], b1[j][kk], acc[i][j + 2], 0, 0, 0);
        __builtin_amdgcn_s_setprio(0);
        __builtin_amdgcn_s_barrier();

        // ---- P3: A half 1 (reuse af regs) ; MFMA quad (mh1, nh1) ----
#pragma unroll
        for (int i = 0; i < 4; ++i) {
            int row = wm * 128 + 64 + i * 16 + l16;
#pragma unroll
            for (int kk = 0; kk < 2; ++kk)
                af[i][kk] = *(const bf16x8*)(AsP + row * 64 + (((kk * 4 + quad) ^ (row & 7)) * 8));
        }
        __builtin_amdgcn_s_barrier();
        __builtin_amdgcn_s_setprio(1);
#pragma unroll
        for (int i = 0; i < 4; ++i)
#pragma unroll
            for (int j = 0; j < 2; ++j)
#pragma unroll
                for (int kk = 0; kk < 2; ++kk)
                    acc[i + 4][j + 2] = __builtin_amdgcn_mfma_f32_16x16x32_bf16(af[i][kk], b1[j][kk], acc[i + 4][j + 2], 0, 0, 0);
        __builtin_amdgcn_s_setprio(0);
        __builtin_amdgcn_s_barrier();

        // ---- P4: stage t+2 (no LDS reads this phase) ; MFMA quad (mh1, nh0) ----
        if (t + 2 < nt) stage_tile(t + 2);
        __builtin_amdgcn_s_barrier();
        __builtin_amdgcn_s_setprio(1);
#pragma unroll
        for (int i = 0; i < 4; ++i)
#pragma unroll
            for (int j = 0; j < 2; ++j)
#pragma unroll
                for (int kk = 0; kk < 2; ++kk)
                    acc[i + 4][j] = __builtin_amdgcn_mfma_f32_16x16x32_bf16(af[i][kk], b0[j][kk], acc[i + 4][j], 0, 0, 0);
        __builtin_amdgcn_s_setprio(0);
        if (t + 2 < nt) { asm volatile("s_waitcnt vmcnt(8)" ::: "memory"); }
        else            { asm volatile("s_waitcnt vmcnt(0)" ::: "memory"); }
        __builtin_amdgcn_s_barrier();
    }

    // ---- epilogue ----
    float* Cz = nullptr;
    if (EPI == 4) Cz = (z == 0) ? (float*)C0 : (z == 1) ? (float*)C1 : (z == 2) ? (float*)C2v : (float*)C3;
#pragma unroll
    for (int i = 0; i < 8; ++i) {
        int row = m0 + wm * 128 + i * 16 + quad * 4;
#pragma unroll
        for (int j = 0; j < 4; ++j) {
            int col = n0 + wn * 64 + j * 16 + l16;
            float bv = (EPI == 2) ? bias[col] : 0.f;
#pragma unroll
            for (int r = 0; r < 4; ++r) {
                float v = acc[i][j][r];
                if (EPI == 2) v = gelu_exact(v + bv);
                size_t idx = (size_t)(row + r) * N + col;
                if (EPI == 4) Cz[idx] = v;
                else          ((bf16*)C0)[idx] = (bf16)v;
            }
        }
    }
}

// ---------------- flash attention (r10: 512-thread blocks, staging amortized 2x) ----------------
__global__ __launch_bounds__(512, 4) void flash_attn(const bf16* __restrict__ qkv,
                                                     const unsigned long long* __restrict__ maskb,
                                                     bf16* __restrict__ o) {
    __shared__ __align__(16) bf16 Ks[128 * 64];    // swizzled packed [t][g^(t&7)]
    __shared__ __align__(16) bf16 Vts[64 * 136];   // [d][tc], tc = t-permuted, pad 8
    const int tid  = threadIdx.x;
    const int lane = tid & 63;
    const int wave = tid >> 6;      // 0..7
    const int l16  = lane & 15;
    const int quad = lane >> 4;
    const int bh = blockIdx.y;
    const int b = bh >> 4, h = bh & 15;
    const int q0 = blockIdx.x * 128;
    const size_t rowb = (size_t)b * SS;
    const float SCL = 0.18033688011112042f;  // 0.125 * log2(e)

    const size_t qrow = (rowb + q0 + wave * 16 + l16) * 3072 + h * 64;
    bf16x8 qf[2];
    {
        bf16x8 q0r = *(const bf16x8*)(qkv + qrow + quad * 8);
        bf16x8 q1r = *(const bf16x8*)(qkv + qrow + 32 + quad * 8);
#pragma unroll
        for (int j = 0; j < 8; ++j) {
            qf[0][j] = (bf16)((float)q0r[j] * SCL);
            qf[1][j] = (bf16)((float)q1r[j] * SCL);
        }
    }

    f32x4 oacc[4];
#pragma unroll
    for (int d = 0; d < 4; ++d) oacc[d] = (f32x4){0.f, 0.f, 0.f, 0.f};
    f32x4 lacc = (f32x4){0.f, 0.f, 0.f, 0.f};
    const int mrow32 = (q0 + wave * 16 + l16) * 32;

    bf16x8 ones;
#pragma unroll
    for (int j = 0; j < 8; ++j) ones[j] = (bf16)1.0f;

    const int vt_tc = (lane >> 4) * 32 + ((lane >> 1) & 3) * 8 + ((lane >> 3) & 1) * 4 + 2 * (lane & 1);
    const int vd8 = wave * 8;

    int kst[2], ksg[2];
#pragma unroll
    for (int c = 0; c < 2; ++c) {
        int gi = (wave * 2 + c) * 64 + lane;
        kst[c] = gi >> 3;
        ksg[c] = (gi & 7) ^ (kst[c] & 7);
    }

    bf16x8 kreg[2], vreg[2];
    ulonglong2 mwreg;
#pragma unroll
    for (int c = 0; c < 2; ++c)
        kreg[c] = *(const bf16x8*)(qkv + (rowb + kst[c]) * 3072 + 1024 + h * 64 + ksg[c] * 8);
    {
        const bf16* vg = qkv + (rowb + 2 * lane) * 3072 + 2048 + h * 64 + vd8;
        vreg[0] = *(const bf16x8*)(vg);
        vreg[1] = *(const bf16x8*)(vg + 3072);
    }
    mwreg = *(const ulonglong2*)(maskb + mrow32);

    for (int kt = 0; kt < SS / 128; ++kt) {
        __syncthreads();
#pragma unroll
        for (int c = 0; c < 2; ++c)
            *(bf16x8*)(Ks + (wave * 2 + c) * 512 + lane * 8) = kreg[c];
#pragma unroll
        for (int j = 0; j < 8; ++j) {
            bf16x2 pr; pr[0] = vreg[0][j]; pr[1] = vreg[1][j];
            *(bf16x2*)(Vts + (vd8 + j) * 136 + vt_tc) = pr;
        }
        ulonglong2 mw = mwreg;
        __syncthreads();

        if (kt + 1 < SS / 128) {
            const int t0n = (kt + 1) * 128;
#pragma unroll
            for (int c = 0; c < 2; ++c)
                kreg[c] = *(const bf16x8*)(qkv + (rowb + t0n + kst[c]) * 3072 + 1024 + h * 64 + ksg[c] * 8);
            {
                const bf16* vg = qkv + (rowb + t0n + 2 * lane) * 3072 + 2048 + h * 64 + vd8;
                vreg[0] = *(const bf16x8*)(vg);
                vreg[1] = *(const bf16x8*)(vg + 3072);
            }
            mwreg = *(const ulonglong2*)(maskb + mrow32 + (kt + 1) * 2);
        }

        f32x4 st[8];
        __builtin_amdgcn_s_setprio(1);
#pragma unroll
        for (int tg = 0; tg < 8; ++tg) {
            int tl = tg * 16 + l16;
            bf16x8 a0 = *(const bf16x8*)(Ks + tl * 64 + ((quad       ^ (tl & 7)) * 8));
            bf16x8 a1 = *(const bf16x8*)(Ks + tl * 64 + (((4 + quad) ^ (tl & 7)) * 8));
            f32x4 s = (f32x4){0.f, 0.f, 0.f, 0.f};
            s = __builtin_amdgcn_mfma_f32_16x16x32_bf16(a0, qf[0], s, 0, 0, 0);
            s = __builtin_amdgcn_mfma_f32_16x16x32_bf16(a1, qf[1], s, 0, 0, 0);
            st[tg] = s;
        }
        __builtin_amdgcn_s_setprio(0);

        unsigned long long s0 = mw.x >> (quad * 4);
        unsigned long long s1 = mw.y >> (quad * 4);
        bf16x8 pva[4];
#pragma unroll
        for (int tg = 0; tg < 8; ++tg) {
            unsigned int bits = (unsigned int)(((tg < 4) ? s0 : s1) >> ((tg & 3) * 16));
#pragma unroll
            for (int r = 0; r < 4; ++r) {
                float p = __builtin_amdgcn_exp2f(st[tg][r]);
                p = ((bits >> r) & 1u) ? 0.f : p;
                pva[tg >> 1][(tg & 1) * 4 + r] = (bf16)p;
            }
        }

        __builtin_amdgcn_s_setprio(1);
#pragma unroll
        for (int kc = 0; kc < 4; ++kc) {
#pragma unroll
            for (int dg = 0; dg < 4; ++dg) {
                bf16x8 bfrag = *(const bf16x8*)(Vts + (dg * 16 + l16) * 136 + kc * 32 + quad * 8);
                oacc[dg] = __builtin_amdgcn_mfma_f32_16x16x32_bf16(pva[kc], bfrag, oacc[dg], 0, 0, 0);
            }
            lacc = __builtin_amdgcn_mfma_f32_16x16x32_bf16(pva[kc], ones, lacc, 0, 0, 0);
        }
        __builtin_amdgcn_s_setprio(0);
    }

#pragma unroll
    for (int r = 0; r < 4; ++r) {
        float inv_l = 1.f / lacc[r];
        bf16* orow = o + (rowb + q0 + wave * 16 + quad * 4 + r) * DD + h * 64;
#pragma unroll
        for (int dg = 0; dg < 4; ++dg)
            orow[dg * 16 + l16] = (bf16)(oacc[dg][r] * inv_l);
    }
}

// ---------------- fused split-K reduce + bias (+gelu) + residual LayerNorm ----------------
// out = resid + LN(act(p0 + .. + p{NP-1} + bias)) * g + b ;  act = gelu if GELU else identity
template <bool GELU, bool WB16, int NP>
__global__ __launch_bounds__(256) void ln_fused(const float* __restrict__ resid,
                                                const float* __restrict__ p0,
                                                const float* __restrict__ p1,
                                                const float* __restrict__ p2,
                                                const float* __restrict__ p3,
                                                const float* __restrict__ bias,
                                                const float* __restrict__ g,
                                                const float* __restrict__ bb,
                                                float* __restrict__ outf,
                                                bf16* __restrict__ outb) {
    const int row = blockIdx.x;
    const int tid = threadIdx.x;
    const size_t base = (size_t)row * DD + tid * 4;
    float4 a0 = *(const float4*)(p0 + base);
    float4 a1 = *(const float4*)(p1 + base);
    float4 bz = *(const float4*)(bias + tid * 4);
    float ax = a0.x + a1.x + bz.x;
    float ay = a0.y + a1.y + bz.y;
    float az = a0.z + a1.z + bz.z;
    float aw = a0.w + a1.w + bz.w;
    if (NP == 4) {
        float4 a2 = *(const float4*)(p2 + base);
        float4 a3 = *(const float4*)(p3 + base);
        ax += a2.x + a3.x; ay += a2.y + a3.y; az += a2.z + a3.z; aw += a2.w + a3.w;
    }
    if (GELU) { ax = gelu_exact(ax); ay = gelu_exact(ay); az = gelu_exact(az); aw = gelu_exact(aw); }
    float s1 = ax + ay + az + aw;
    float s2 = ax * ax + ay * ay + az * az + aw * aw;
#pragma unroll
    for (int off = 32; off; off >>= 1) {
        s1 += __shfl_xor(s1, off, 64);
        s2 += __shfl_xor(s2, off, 64);
    }
    __shared__ float red[8];
    if ((tid & 63) == 0) { red[(tid >> 6) * 2] = s1; red[(tid >> 6) * 2 + 1] = s2; }
    __syncthreads();
    s1 = red[0] + red[2] + red[4] + red[6];
    s2 = red[1] + red[3] + red[5] + red[7];
    float mean = s1 * (1.f / DD);
    float var  = s2 * (1.f / DD) - mean * mean;
    float rs = rsqrtf(var + 1e-5f);
    float4 gv = *(const float4*)(g + tid * 4);
    float4 bv = *(const float4*)(bb + tid * 4);
    float4 rv = *(const float4*)(resid + base);
    float y0 = rv.x + (ax - mean) * rs * gv.x + bv.x;
    float y1 = rv.y + (ay - mean) * rs * gv.y + bv.y;
    float y2 = rv.z + (az - mean) * rs * gv.z + bv.z;
    float y3 = rv.w + (aw - mean) * rs * gv.w + bv.w;
    float4 yo = make_float4(y0, y1, y2, y3);
    *(float4*)(outf + base) = yo;
    if (WB16) {
        bf16x4 ob;
        ob[0] = (bf16)y0; ob[1] = (bf16)y1; ob[2] = (bf16)y2; ob[3] = (bf16)y3;
        *(bf16x4*)(outb + base) = ob;
    }
}

// ---------------- launcher ----------------
extern "C" void kernel_launch(void* const* d_in, const int* in_sizes, int n_in,
                              void* d_out, int out_size, void* d_ws, size_t ws_size,
                              hipStream_t stream) {
    const float* x    = (const float*)d_in[0];
    const int*   mask = (const int*)d_in[1];
    const float* Wq   = (const float*)d_in[2];
    const float* Wk   = (const float*)d_in[3];
    const float* Wv   = (const float*)d_in[4];
    const float* Wo   = (const float*)d_in[5];
    const float* bo   = (const float*)d_in[6];
    const float* ln1g = (const float*)d_in[7];
    const float* ln1b = (const float*)d_in[8];
    const float* W1   = (const float*)d_in[9];
    const float* b1   = (const float*)d_in[10];
    const float* W2   = (const float*)d_in[11];
    const float* b2   = (const float*)d_in[12];
    const float* ln2g = (const float*)d_in[13];
    const float* ln2b = (const float*)d_in[14];

    char* w = (char*)d_ws;
    bf16* Wqkv_t = (bf16*)w; w += (size_t)3072 * 1024 * 2;   // 6 MB
    bf16* Wo_t   = (bf16*)w; w += (size_t)1024 * 1024 * 2;   // 2 MB
    bf16* W1_t   = (bf16*)w; w += (size_t)4096 * 1024 * 2;   // 8 MB
    bf16* W2_t   = (bf16*)w; w += (size_t)1024 * 4096 * 2;   // 8 MB
    bf16* x_b    = (bf16*)w; w += (size_t)MROWS * DD * 2;    // 8 MB (then o_b, x1_b, FFN2 fp1)
    bf16* qkv    = (bf16*)w; w += (size_t)MROWS * 3072 * 2;  // 24 MB (then FFN2 fp1 tail / fp2)
    float* R     = (float*)w; w += (size_t)MROWS * DD * 8;   // 32 MB (O-proj p0/p1, then h_b)
    float* x1_f  = (float*)w; w += (size_t)MROWS * DD * 4;   // 16 MB
    unsigned long long* maskb = (unsigned long long*)w; w += (size_t)SS * 32 * 8;  // 0.5 MB  (total 104.5)
    bf16* o_b  = x_b;                 // alive: attention -> O-proj
    bf16* x1_b = x_b;                 // alive: LN1 -> FFN1
    float* op0 = R;                   // O-proj partial z=0
    float* op1 = R + (size_t)MROWS * DD;  // O-proj partial z=1
    bf16*  h_b = (bf16*)R;            // FFN1 out (32 MB; partials dead by then)
    // FFN2 split-4 fp32 partials (16 MB each), all regions dead by FFN2 time:
    float* fp0 = (float*)d_out;                            // reduced in-place by LN2
    float* fp1 = (float*)x_b;                              // x_b (8 MB) + qkv head (8 MB), contiguous
    float* fp2 = (float*)x_b + (size_t)4 * 1024 * 1024;    // qkv tail (16 MB)
    float* fp3 = (float*)d_ws;                             // Wqkv_t+Wo_t+W1_t (16 MB, dead after FFN1)

    // fused prep (one launch)
    prep_kernel<<<32768, 256, 0, stream>>>(x, x_b, mask, maskb,
                                           Wq, Wk, Wv, Wo, W1, W2,
                                           Wqkv_t, Wo_t, W1_t, W2_t);

    // QKV projection: [4096,1024] x [1024,3072] -> qkv bf16  (256^2 8-phase)
    gemm256<0><<<dim3(12, 16, 1), 512, 0, stream>>>(x_b, Wqkv_t, qkv, nullptr, nullptr, nullptr, nullptr, MROWS, 3072, 1024, 1024);
    // attention (512-thread blocks, 128 q-rows each)
    flash_attn<<<dim3(SS / 128, BB * HH), 512, 0, stream>>>(qkv, maskb, o_b);
    // O-proj, split-K=2 -> fp32 partials (bias deferred to LN1)
    gemm_bt<4><<<dim3(8, 32, 2), 256, 0, stream>>>(o_b, Wo_t, op0, op1, nullptr, MROWS, 1024, 512, 1024);
    // x1 = x + LN(op0+op1+bo)
    ln_fused<false, true, 2><<<MROWS, 256, 0, stream>>>(x, op0, op1, nullptr, nullptr, bo, ln1g, ln1b, x1_f, x1_b);
    // FFN1: gelu(x1@W1 + b1) -> bf16  (256^2 8-phase)
    gemm256<2><<<dim3(16, 16, 1), 512, 0, stream>>>(x1_b, W1_t, h_b, nullptr, nullptr, nullptr, b1, MROWS, 4096, 1024, 1024);
    // FFN2, split-K=4 -> fp32 partials (bias+gelu deferred to LN2)  (256^2 8-phase)
    gemm256<4><<<dim3(4, 16, 4), 512, 0, stream>>>(h_b, W2_t, fp0, fp1, fp2, fp3, nullptr, MROWS, 1024, 1024, 4096);
    // out = x1 + LN(gelu(fp0+fp1+fp2+fp3+b2))  (fp32, in-place on d_out)
    ln_fused<true, false, 4><<<MROWS, 256, 0, stream>>>(x1_f, fp0, fp1, fp2, fp3, b2, ln2g, ln2b, (float*)d_out, nullptr);
}

// Round 4
// 374.201 us; speedup vs baseline: 1.1704x; 1.1704x over previous
//
#include <hip/hip_runtime.h>
#include <hip/hip_bf16.h>
#include <cstdint>

// Problem constants
#define BB 2
#define SS 2048
#define DD 1024
#define HH 16
#define HDIM 64
#define MROWS (BB*SS)   // 4096

typedef __bf16 bf16;
using bf16x8 = __bf16 __attribute__((ext_vector_type(8)));
using bf16x4 = __bf16 __attribute__((ext_vector_type(4)));
using bf16x2 = __bf16 __attribute__((ext_vector_type(2)));
using f32x4  = float __attribute__((ext_vector_type(4)));

__device__ __forceinline__ float gelu_exact(float x) {
    return 0.5f * x * (1.f + erff(x * 0.70710678118654752f));
}

// global->LDS direct DMA, 16B per lane (lane i deposits at base + i*16).
__device__ __forceinline__ void stage16(const bf16* g, bf16* lds_chunk_base, int lane) {
#if __has_builtin(__builtin_amdgcn_global_load_lds)
    __builtin_amdgcn_global_load_lds((const __attribute__((address_space(1))) void*)g,
                                     (__attribute__((address_space(3))) void*)lds_chunk_base,
                                     16, 0, 0);
#else
    *(bf16x8*)(lds_chunk_base + lane * 8) = *(const bf16x8*)g;
#endif
}

// ---------------- fused prep: cast x, pack mask, transpose all weights ----------------
// block ranges: [0,4096) cast x | [4096,20480) pack mask | [20480,32768) transposes
__global__ __launch_bounds__(256) void prep_kernel(
    const float* __restrict__ x, bf16* __restrict__ x_b,
    const int* __restrict__ mask, unsigned long long* __restrict__ maskb,
    const float* __restrict__ Wq, const float* __restrict__ Wk,
    const float* __restrict__ Wv, const float* __restrict__ Wo,
    const float* __restrict__ W1, const float* __restrict__ W2,
    bf16* __restrict__ Wqkv_t, bf16* __restrict__ Wo_t,
    bf16* __restrict__ W1_t, bf16* __restrict__ W2_t) {
    const int bid = blockIdx.x;
    if (bid < 4096) {
        int i = bid * 256 + threadIdx.x;
        float4 v = ((const float4*)x)[i];
        bf16x4 o;
        o[0] = (bf16)v.x; o[1] = (bf16)v.y; o[2] = (bf16)v.z; o[3] = (bf16)v.w;
        *(bf16x4*)(x_b + (size_t)i * 4) = o;
        return;
    }
    if (bid < 20480) {
        int gid = (bid - 4096) * 256 + threadIdx.x;
        int mv = mask[gid];
        unsigned long long bal = __ballot(mv == 1);
        if ((threadIdx.x & 63) == 0) maskb[gid >> 6] = bal;
        return;
    }
    int t = bid - 20480;
    const float* W; bf16* Wt; int K, N, bx, by;
    if (t < 4096) {
        int wsel = t >> 10;
        int tt = t & 1023;
        W  = (wsel == 0) ? Wq : (wsel == 1) ? Wk : (wsel == 2) ? Wv : Wo;
        Wt = (wsel == 3) ? Wo_t : (Wqkv_t + (size_t)wsel * 1024 * 1024);
        K = 1024; N = 1024; bx = (tt & 31) * 32; by = (tt >> 5) * 32;
    } else if (t < 8192) {
        int tt = t - 4096;
        W = W1; Wt = W1_t; K = 1024; N = 4096;
        bx = (tt & 127) * 32; by = (tt >> 7) * 32;
    } else {
        int tt = t - 8192;
        W = W2; Wt = W2_t; K = 4096; N = 1024;
        bx = (tt & 31) * 32; by = (tt >> 5) * 32;
    }
    __shared__ float tile[32][33];
    int tx = threadIdx.x & 31;
    int ty = threadIdx.x >> 5;
#pragma unroll
    for (int j = 0; j < 4; ++j)
        tile[ty + j * 8][tx] = W[(size_t)(by + ty + j * 8) * N + bx + tx];
    __syncthreads();
#pragma unroll
    for (int j = 0; j < 4; ++j)
        Wt[(size_t)(bx + ty + j * 8) * K + by + tx] = (bf16)tile[tx][ty + j * 8];
}

// ---------------- bf16 MFMA GEMM: C = A(M x ldk) * Bt(N x ldk)^T, 128x128 tile ----------------
// K = slice length along k (z selects slice); ldk = full row stride.
// EPI: 0 = store bf16 raw; 2 = +bias,gelu store bf16; 4 = raw fp32 partial to (z ? C2 : C).
// T1: bijective XCD swizzle on the linear dispatch index (all grids here are %8==0),
// so each XCD's L2 holds a contiguous run of M-panels instead of 8x-duplicating A.
template <int EPI>
__global__ __launch_bounds__(256, 3) void gemm_bt(const bf16* __restrict__ A,
                                                  const bf16* __restrict__ Bt,
                                                  void* __restrict__ C,
                                                  void* __restrict__ C2,
                                                  const float* __restrict__ bias,
                                                  int M, int N, int K, int ldk) {
    __shared__ __align__(16) bf16 As[128 * 64];
    __shared__ __align__(16) bf16 Bs[128 * 64];
    const int tid  = threadIdx.x;
    const int lane = tid & 63;
    const int wave = tid >> 6;
    const int l16  = lane & 15;
    const int quad = lane >> 4;
    const int wm = wave >> 1, wn = wave & 1;

    int bx, by, bz;
    {
        const int Gx = gridDim.x, Gy = gridDim.y, Gz = gridDim.z;
        const int nwg = Gx * Gy * Gz;
        int L = blockIdx.x + Gx * (blockIdx.y + Gy * blockIdx.z);
        if ((nwg & 7) == 0) {
            int chunk = nwg >> 3;
            L = (L & 7) * chunk + (L >> 3);
        }
        bx = L % Gx; int rest = L / Gx; by = rest % Gy; bz = rest / Gy;
    }
    const int m0 = by * 128, n0 = bx * 128;
    const int z  = bz;
    A  += (size_t)z * K;
    Bt += (size_t)z * K;

    f32x4 acc[4][4];
#pragma unroll
    for (int i = 0; i < 4; ++i)
#pragma unroll
        for (int j = 0; j < 4; ++j) acc[i][j] = (f32x4){0.f, 0.f, 0.f, 0.f};

    const int nsteps = K >> 6;
    for (int kt = 0; kt < nsteps; ++kt) {
        const int kbase = kt << 6;
#pragma unroll
        for (int c = 0; c < 4; ++c) {
            int chunk = wave * 4 + c;
            int gi = chunk * 64 + lane;
            int m  = gi >> 3;
            int cp = gi & 7;
            int g  = cp ^ (m & 7);
            stage16(A  + (size_t)(m0 + m) * ldk + kbase + g * 8, As + chunk * 512, lane);
            stage16(Bt + (size_t)(n0 + m) * ldk + kbase + g * 8, Bs + chunk * 512, lane);
        }
        __syncthreads();
#pragma unroll
        for (int ks = 0; ks < 2; ++ks) {
            bf16x8 af[4], bfr[4];
#pragma unroll
            for (int i = 0; i < 4; ++i) {
                int m = wm * 64 + i * 16 + l16;
                int g = ks * 4 + quad;
                af[i]  = *(const bf16x8*)(As + m * 64 + ((g ^ (m & 7)) * 8));
                int n = wn * 64 + i * 16 + l16;
                bfr[i] = *(const bf16x8*)(Bs + n * 64 + ((g ^ (n & 7)) * 8));
            }
#pragma unroll
            for (int i = 0; i < 4; ++i)
#pragma unroll
                for (int j = 0; j < 4; ++j)
                    acc[i][j] = __builtin_amdgcn_mfma_f32_16x16x32_bf16(af[i], bfr[j], acc[i][j], 0, 0, 0);
        }
        __syncthreads();
    }

    float* Cz = (EPI == 4) ? (z ? (float*)C2 : (float*)C) : nullptr;
#pragma unroll
    for (int i = 0; i < 4; ++i) {
        int row = m0 + wm * 64 + i * 16 + quad * 4;
#pragma unroll
        for (int j = 0; j < 4; ++j) {
            int col = n0 + wn * 64 + j * 16 + l16;
            float bv = (EPI == 2) ? bias[col] : 0.f;
#pragma unroll
            for (int r = 0; r < 4; ++r) {
                float v = acc[i][j][r];
                if (EPI == 2) v = gelu_exact(v + bv);
                size_t idx = (size_t)(row + r) * N + col;
                if (EPI == 4) Cz[idx] = v;
                else          ((bf16*)C)[idx] = (bf16)v;
            }
        }
    }
}

// ---------------- flash attention (r11: r10 + XCD swizzle for K/V L2 locality) ----------------
// grid: (S/128, B*H), block 512 (8 waves; wave owns 16 query rows; 128 q-rows/block).
// T1 swizzle: 512 blocks, chunk=64 -> each XCD owns 4 whole heads; that head's K/V
// (0.5 MB each) stays resident in its XCD L2 instead of being duplicated into all 8.
__global__ __launch_bounds__(512, 4) void flash_attn(const bf16* __restrict__ qkv,
                                                     const unsigned long long* __restrict__ maskb,
                                                     bf16* __restrict__ o) {
    __shared__ __align__(16) bf16 Ks[128 * 64];    // swizzled packed [t][g^(t&7)]
    __shared__ __align__(16) bf16 Vts[64 * 136];   // [d][tc], tc = t-permuted, pad 8
    const int tid  = threadIdx.x;
    const int lane = tid & 63;
    const int wave = tid >> 6;      // 0..7
    const int l16  = lane & 15;
    const int quad = lane >> 4;

    int bqx, bhy;
    {
        const int Gx = gridDim.x, Gy = gridDim.y;
        int L = blockIdx.x + Gx * blockIdx.y;
        int chunk = (Gx * Gy) >> 3;
        L = (L & 7) * chunk + (L >> 3);
        bqx = L % Gx; bhy = L / Gx;
    }
    const int bh = bhy;
    const int b = bh >> 4, h = bh & 15;
    const int q0 = bqx * 128;
    const size_t rowb = (size_t)b * SS;
    const float SCL = 0.18033688011112042f;  // 0.125 * log2(e)

    // Q fragments, pre-scaled by SCL (so softmax is exp2(st) directly)
    const size_t qrow = (rowb + q0 + wave * 16 + l16) * 3072 + h * 64;
    bf16x8 qf[2];
    {
        bf16x8 q0r = *(const bf16x8*)(qkv + qrow + quad * 8);
        bf16x8 q1r = *(const bf16x8*)(qkv + qrow + 32 + quad * 8);
#pragma unroll
        for (int j = 0; j < 8; ++j) {
            qf[0][j] = (bf16)((float)q0r[j] * SCL);
            qf[1][j] = (bf16)((float)q1r[j] * SCL);
        }
    }

    f32x4 oacc[4];
#pragma unroll
    for (int d = 0; d < 4; ++d) oacc[d] = (f32x4){0.f, 0.f, 0.f, 0.f};
    f32x4 lacc = (f32x4){0.f, 0.f, 0.f, 0.f};
    const int mrow32 = (q0 + wave * 16 + l16) * 32;

    bf16x8 ones;
#pragma unroll
    for (int j = 0; j < 8; ++j) ones[j] = (bf16)1.0f;

    // V staging geometry: thread handles t-pair = 2*lane for d-granule d8 = wave*8;
    // permuted col tc groups the 8 k-slots of each (kc,quad) contiguously.
    const int vt_tc = (lane >> 4) * 32 + ((lane >> 1) & 3) * 8 + ((lane >> 3) & 1) * 4 + 2 * (lane & 1);
    const int vd8 = wave * 8;

    // K staging geometry (constant across kt): 2 chunks per wave
    int kst[2], ksg[2];
#pragma unroll
    for (int c = 0; c < 2; ++c) {
        int gi = (wave * 2 + c) * 64 + lane;
        kst[c] = gi >> 3;
        ksg[c] = (gi & 7) ^ (kst[c] & 7);
    }

    // -------- prologue: prefetch tile 0 into registers --------
    bf16x8 kreg[2], vreg[2];
    ulonglong2 mwreg;
#pragma unroll
    for (int c = 0; c < 2; ++c)
        kreg[c] = *(const bf16x8*)(qkv + (rowb + kst[c]) * 3072 + 1024 + h * 64 + ksg[c] * 8);
    {
        const bf16* vg = qkv + (rowb + 2 * lane) * 3072 + 2048 + h * 64 + vd8;
        vreg[0] = *(const bf16x8*)(vg);
        vreg[1] = *(const bf16x8*)(vg + 3072);
    }
    mwreg = *(const ulonglong2*)(maskb + mrow32);

    for (int kt = 0; kt < SS / 128; ++kt) {
        __syncthreads();  // previous tile's compute done before overwrite
        // commit staged K (swizzled layout)
#pragma unroll
        for (int c = 0; c < 2; ++c)
            *(bf16x8*)(Ks + (wave * 2 + c) * 512 + lane * 8) = kreg[c];
        // commit staged V, transposed+permuted (8 bf16x2 writes per thread)
#pragma unroll
        for (int j = 0; j < 8; ++j) {
            bf16x2 pr; pr[0] = vreg[0][j]; pr[1] = vreg[1][j];
            *(bf16x2*)(Vts + (vd8 + j) * 136 + vt_tc) = pr;
        }
        ulonglong2 mw = mwreg;
        __syncthreads();

        // prefetch next tile into regs: latency hides under this tile's compute.
        if (kt + 1 < SS / 128) {
            const int t0n = (kt + 1) * 128;
#pragma unroll
            for (int c = 0; c < 2; ++c)
                kreg[c] = *(const bf16x8*)(qkv + (rowb + t0n + kst[c]) * 3072 + 1024 + h * 64 + ksg[c] * 8);
            {
                const bf16* vg = qkv + (rowb + t0n + 2 * lane) * 3072 + 2048 + h * 64 + vd8;
                vreg[0] = *(const bf16x8*)(vg);
                vreg[1] = *(const bf16x8*)(vg + 3072);
            }
            mwreg = *(const ulonglong2*)(maskb + mrow32 + (kt + 1) * 2);
        }

        // S^T tiles: D[t][s], t = tg*16 + quad*4 + reg, s = l16
        f32x4 st[8];
        __builtin_amdgcn_s_setprio(1);
#pragma unroll
        for (int tg = 0; tg < 8; ++tg) {
            int tl = tg * 16 + l16;
            bf16x8 a0 = *(const bf16x8*)(Ks + tl * 64 + ((quad       ^ (tl & 7)) * 8));
            bf16x8 a1 = *(const bf16x8*)(Ks + tl * 64 + (((4 + quad) ^ (tl & 7)) * 8));
            f32x4 s = (f32x4){0.f, 0.f, 0.f, 0.f};
            s = __builtin_amdgcn_mfma_f32_16x16x32_bf16(a0, qf[0], s, 0, 0, 0);
            s = __builtin_amdgcn_mfma_f32_16x16x32_bf16(a1, qf[1], s, 0, 0, 0);
            st[tg] = s;
        }
        __builtin_amdgcn_s_setprio(0);

        // exp2 + mask-zero + pack P fragments (Q pre-scaled: no mul here)
        unsigned long long s0 = mw.x >> (quad * 4);
        unsigned long long s1 = mw.y >> (quad * 4);
        bf16x8 pva[4];
#pragma unroll
        for (int tg = 0; tg < 8; ++tg) {
            unsigned int bits = (unsigned int)(((tg < 4) ? s0 : s1) >> ((tg & 3) * 16));
#pragma unroll
            for (int r = 0; r < 4; ++r) {
                float p = __builtin_amdgcn_exp2f(st[tg][r]);
                p = ((bits >> r) & 1u) ? 0.f : p;
                pva[tg >> 1][(tg & 1) * 4 + r] = (bf16)p;
            }
        }

        // O += P*V ; lsum += P*ones (row-sums on the MFMA pipe, layout row=quad*4+r)
        __builtin_amdgcn_s_setprio(1);
#pragma unroll
        for (int kc = 0; kc < 4; ++kc) {
#pragma unroll
            for (int dg = 0; dg < 4; ++dg) {
                bf16x8 bfrag = *(const bf16x8*)(Vts + (dg * 16 + l16) * 136 + kc * 32 + quad * 8);
                oacc[dg] = __builtin_amdgcn_mfma_f32_16x16x32_bf16(pva[kc], bfrag, oacc[dg], 0, 0, 0);
            }
            lacc = __builtin_amdgcn_mfma_f32_16x16x32_bf16(pva[kc], ones, lacc, 0, 0, 0);
        }
        __builtin_amdgcn_s_setprio(0);
    }

    // epilogue: lacc[r] already holds the P row-sum for q-row quad*4+r
#pragma unroll
    for (int r = 0; r < 4; ++r) {
        float inv_l = 1.f / lacc[r];
        bf16* orow = o + (rowb + q0 + wave * 16 + quad * 4 + r) * DD + h * 64;
#pragma unroll
        for (int dg = 0; dg < 4; ++dg)
            orow[dg * 16 + l16] = (bf16)(oacc[dg][r] * inv_l);
    }
}

// ---------------- fused split-K reduce + bias (+gelu) + residual LayerNorm ----------------
// out = resid + LN(act(p0 + p1 + bias)) * g + b ;  act = gelu if GELU else identity
template <bool GELU, bool WB16>
__global__ __launch_bounds__(256) void ln_fused(const float* __restrict__ resid,
                                                const float* __restrict__ p0,
                                                const float* __restrict__ p1,
                                                const float* __restrict__ bias,
                                                const float* __restrict__ g,
                                                const float* __restrict__ bb,
                                                float* __restrict__ outf,
                                                bf16* __restrict__ outb) {
    const int row = blockIdx.x;
    const int tid = threadIdx.x;
    const size_t base = (size_t)row * DD + tid * 4;
    float4 a0 = *(const float4*)(p0 + base);
    float4 a1 = *(const float4*)(p1 + base);
    float4 bz = *(const float4*)(bias + tid * 4);
    float ax = a0.x + a1.x + bz.x;
    float ay = a0.y + a1.y + bz.y;
    float az = a0.z + a1.z + bz.z;
    float aw = a0.w + a1.w + bz.w;
    if (GELU) { ax = gelu_exact(ax); ay = gelu_exact(ay); az = gelu_exact(az); aw = gelu_exact(aw); }
    float s1 = ax + ay + az + aw;
    float s2 = ax * ax + ay * ay + az * az + aw * aw;
#pragma unroll
    for (int off = 32; off; off >>= 1) {
        s1 += __shfl_xor(s1, off, 64);
        s2 += __shfl_xor(s2, off, 64);
    }
    __shared__ float red[8];
    if ((tid & 63) == 0) { red[(tid >> 6) * 2] = s1; red[(tid >> 6) * 2 + 1] = s2; }
    __syncthreads();
    s1 = red[0] + red[2] + red[4] + red[6];
    s2 = red[1] + red[3] + red[5] + red[7];
    float mean = s1 * (1.f / DD);
    float var  = s2 * (1.f / DD) - mean * mean;
    float rs = rsqrtf(var + 1e-5f);
    float4 gv = *(const float4*)(g + tid * 4);
    float4 bv = *(const float4*)(bb + tid * 4);
    float4 rv = *(const float4*)(resid + base);
    float y0 = rv.x + (ax - mean) * rs * gv.x + bv.x;
    float y1 = rv.y + (ay - mean) * rs * gv.y + bv.y;
    float y2 = rv.z + (az - mean) * rs * gv.z + bv.z;
    float y3 = rv.w + (aw - mean) * rs * gv.w + bv.w;
    float4 yo = make_float4(y0, y1, y2, y3);
    *(float4*)(outf + base) = yo;
    if (WB16) {
        bf16x4 ob;
        ob[0] = (bf16)y0; ob[1] = (bf16)y1; ob[2] = (bf16)y2; ob[3] = (bf16)y3;
        *(bf16x4*)(outb + base) = ob;
    }
}

// ---------------- launcher ----------------
extern "C" void kernel_launch(void* const* d_in, const int* in_sizes, int n_in,
                              void* d_out, int out_size, void* d_ws, size_t ws_size,
                              hipStream_t stream) {
    const float* x    = (const float*)d_in[0];
    const int*   mask = (const int*)d_in[1];
    const float* Wq   = (const float*)d_in[2];
    const float* Wk   = (const float*)d_in[3];
    const float* Wv   = (const float*)d_in[4];
    const float* Wo   = (const float*)d_in[5];
    const float* bo   = (const float*)d_in[6];
    const float* ln1g = (const float*)d_in[7];
    const float* ln1b = (const float*)d_in[8];
    const float* W1   = (const float*)d_in[9];
    const float* b1   = (const float*)d_in[10];
    const float* W2   = (const float*)d_in[11];
    const float* b2   = (const float*)d_in[12];
    const float* ln2g = (const float*)d_in[13];
    const float* ln2b = (const float*)d_in[14];

    char* w = (char*)d_ws;
    bf16* Wqkv_t = (bf16*)w; w += (size_t)3072 * 1024 * 2;   // 6 MB
    bf16* Wo_t   = (bf16*)w; w += (size_t)1024 * 1024 * 2;   // 2 MB
    bf16* W1_t   = (bf16*)w; w += (size_t)4096 * 1024 * 2;   // 8 MB
    bf16* W2_t   = (bf16*)w; w += (size_t)1024 * 4096 * 2;   // 8 MB
    bf16* x_b    = (bf16*)w; w += (size_t)MROWS * DD * 2;    // 8 MB (then o_b, x1_b)
    bf16* qkv    = (bf16*)w; w += (size_t)MROWS * 3072 * 2;  // 24 MB (then FFN2 p1)
    float* R     = (float*)w; w += (size_t)MROWS * DD * 8;   // 32 MB (O-proj p0/p1, then h_b)
    float* x1_f  = (float*)w; w += (size_t)MROWS * DD * 4;   // 16 MB
    unsigned long long* maskb = (unsigned long long*)w; w += (size_t)SS * 32 * 8;  // 0.5 MB  (total 104.5)
    bf16* o_b  = x_b;                 // alive: attention -> O-proj
    bf16* x1_b = x_b;                 // alive: LN1 -> FFN1
    float* op0 = R;                   // O-proj partial z=0
    float* op1 = R + (size_t)MROWS * DD;  // O-proj partial z=1
    bf16*  h_b = (bf16*)R;            // FFN1 out (32 MB; partials dead by then)
    float* fp0 = (float*)d_out;       // FFN2 partial z=0 (reduced in-place by LN2)
    float* fp1 = (float*)qkv;         // FFN2 partial z=1 (qkv dead after flash)

    // fused prep (one launch)
    prep_kernel<<<32768, 256, 0, stream>>>(x, x_b, mask, maskb,
                                           Wq, Wk, Wv, Wo, W1, W2,
                                           Wqkv_t, Wo_t, W1_t, W2_t);

    // QKV projection: [4096,1024] x [1024,3072] -> qkv bf16
    gemm_bt<0><<<dim3(24, 32, 1), 256, 0, stream>>>(x_b, Wqkv_t, qkv, nullptr, nullptr, MROWS, 3072, 1024, 1024);
    // attention (512-thread blocks, 128 q-rows each)
    flash_attn<<<dim3(SS / 128, BB * HH), 512, 0, stream>>>(qkv, maskb, o_b);
    // O-proj, split-K=2 -> fp32 partials (bias deferred to LN1)
    gemm_bt<4><<<dim3(8, 32, 2), 256, 0, stream>>>(o_b, Wo_t, op0, op1, nullptr, MROWS, 1024, 512, 1024);
    // x1 = x + LN(op0+op1+bo)
    ln_fused<false, true><<<MROWS, 256, 0, stream>>>(x, op0, op1, bo, ln1g, ln1b, x1_f, x1_b);
    // FFN1: gelu(x1@W1 + b1) -> bf16
    gemm_bt<2><<<dim3(32, 32, 1), 256, 0, stream>>>(x1_b, W1_t, h_b, nullptr, b1, MROWS, 4096, 1024, 1024);
    // FFN2, split-K=2 -> fp32 partials (bias+gelu deferred to LN2)
    gemm_bt<4><<<dim3(8, 32, 2), 256, 0, stream>>>(h_b, W2_t, fp0, fp1, nullptr, MROWS, 1024, 2048, 4096);
    // out = x1 + LN(gelu(fp0+fp1+b2))  (fp32, in-place on d_out)
    ln_fused<true, false><<<MROWS, 256, 0, stream>>>(x1_f, fp0, fp1, b2, ln2g, ln2b, (float*)d_out, nullptr);
}

// Round 5
// 371.884 us; speedup vs baseline: 1.1777x; 1.0062x over previous
//
#include <hip/hip_runtime.h>
#include <hip/hip_bf16.h>
#include <cstdint>

// Problem constants
#define BB 2
#define SS 2048
#define DD 1024
#define HH 16
#define HDIM 64
#define MROWS (BB*SS)   // 4096

typedef __bf16 bf16;
using bf16x8 = __bf16 __attribute__((ext_vector_type(8)));
using bf16x4 = __bf16 __attribute__((ext_vector_type(4)));
using bf16x2 = __bf16 __attribute__((ext_vector_type(2)));
using f32x4  = float __attribute__((ext_vector_type(4)));

__device__ __forceinline__ float gelu_exact(float x) {
    return 0.5f * x * (1.f + erff(x * 0.70710678118654752f));
}

// global->LDS direct DMA, 16B per lane (lane i deposits at base + i*16).
__device__ __forceinline__ void stage16(const bf16* g, bf16* lds_chunk_base, int lane) {
#if __has_builtin(__builtin_amdgcn_global_load_lds)
    __builtin_amdgcn_global_load_lds((const __attribute__((address_space(1))) void*)g,
                                     (__attribute__((address_space(3))) void*)lds_chunk_base,
                                     16, 0, 0);
#else
    *(bf16x8*)(lds_chunk_base + lane * 8) = *(const bf16x8*)g;
#endif
}

// 32-bit LDS byte address for inline-asm DS ops
__device__ __forceinline__ unsigned lds_addr(const void* p) {
    return (unsigned)(uintptr_t)(const __attribute__((address_space(3))) void*)p;
}

// inline-asm ds_read_b128: invisible to the compiler's waitcnt pass, so in-flight
// global_load_lds staging is NOT drained before it (the R3 failure mode).
__device__ __forceinline__ bf16x8 dsr(unsigned addr) {
    bf16x8 r;
    asm volatile("ds_read_b128 %0, %1" : "=v"(r) : "v"(addr));
    return r;
}

// ---------------- fused prep: cast x, pack mask, transpose all weights ----------------
__global__ __launch_bounds__(256) void prep_kernel(
    const float* __restrict__ x, bf16* __restrict__ x_b,
    const int* __restrict__ mask, unsigned long long* __restrict__ maskb,
    const float* __restrict__ Wq, const float* __restrict__ Wk,
    const float* __restrict__ Wv, const float* __restrict__ Wo,
    const float* __restrict__ W1, const float* __restrict__ W2,
    bf16* __restrict__ Wqkv_t, bf16* __restrict__ Wo_t,
    bf16* __restrict__ W1_t, bf16* __restrict__ W2_t) {
    const int bid = blockIdx.x;
    if (bid < 4096) {
        int i = bid * 256 + threadIdx.x;
        float4 v = ((const float4*)x)[i];
        bf16x4 o;
        o[0] = (bf16)v.x; o[1] = (bf16)v.y; o[2] = (bf16)v.z; o[3] = (bf16)v.w;
        *(bf16x4*)(x_b + (size_t)i * 4) = o;
        return;
    }
    if (bid < 20480) {
        int gid = (bid - 4096) * 256 + threadIdx.x;
        int mv = mask[gid];
        unsigned long long bal = __ballot(mv == 1);
        if ((threadIdx.x & 63) == 0) maskb[gid >> 6] = bal;
        return;
    }
    int t = bid - 20480;
    const float* W; bf16* Wt; int K, N, bx, by;
    if (t < 4096) {
        int wsel = t >> 10;
        int tt = t & 1023;
        W  = (wsel == 0) ? Wq : (wsel == 1) ? Wk : (wsel == 2) ? Wv : Wo;
        Wt = (wsel == 3) ? Wo_t : (Wqkv_t + (size_t)wsel * 1024 * 1024);
        K = 1024; N = 1024; bx = (tt & 31) * 32; by = (tt >> 5) * 32;
    } else if (t < 8192) {
        int tt = t - 4096;
        W = W1; Wt = W1_t; K = 1024; N = 4096;
        bx = (tt & 127) * 32; by = (tt >> 7) * 32;
    } else {
        int tt = t - 8192;
        W = W2; Wt = W2_t; K = 4096; N = 1024;
        bx = (tt & 31) * 32; by = (tt >> 5) * 32;
    }
    __shared__ float tile[32][33];
    int tx = threadIdx.x & 31;
    int ty = threadIdx.x >> 5;
#pragma unroll
    for (int j = 0; j < 4; ++j)
        tile[ty + j * 8][tx] = W[(size_t)(by + ty + j * 8) * N + bx + tx];
    __syncthreads();
#pragma unroll
    for (int j = 0; j < 4; ++j)
        Wt[(size_t)(bx + ty + j * 8) * K + by + tx] = (bf16)tile[tx][ty + j * 8];
}

// ---------------- bf16 MFMA GEMM: 128x128 tile (O-proj only) ----------------
template <int EPI>
__global__ __launch_bounds__(256, 3) void gemm_bt(const bf16* __restrict__ A,
                                                  const bf16* __restrict__ Bt,
                                                  void* __restrict__ C,
                                                  void* __restrict__ C2,
                                                  const float* __restrict__ bias,
                                                  int M, int N, int K, int ldk) {
    __shared__ __align__(16) bf16 As[128 * 64];
    __shared__ __align__(16) bf16 Bs[128 * 64];
    const int tid  = threadIdx.x;
    const int lane = tid & 63;
    const int wave = tid >> 6;
    const int l16  = lane & 15;
    const int quad = lane >> 4;
    const int wm = wave >> 1, wn = wave & 1;

    int bx, by, bz;
    {
        const int Gx = gridDim.x, Gy = gridDim.y, Gz = gridDim.z;
        const int nwg = Gx * Gy * Gz;
        int L = blockIdx.x + Gx * (blockIdx.y + Gy * blockIdx.z);
        if ((nwg & 7) == 0) {
            int chunk = nwg >> 3;
            L = (L & 7) * chunk + (L >> 3);
        }
        bx = L % Gx; int rest = L / Gx; by = rest % Gy; bz = rest / Gy;
    }
    const int m0 = by * 128, n0 = bx * 128;
    const int z  = bz;
    A  += (size_t)z * K;
    Bt += (size_t)z * K;

    f32x4 acc[4][4];
#pragma unroll
    for (int i = 0; i < 4; ++i)
#pragma unroll
        for (int j = 0; j < 4; ++j) acc[i][j] = (f32x4){0.f, 0.f, 0.f, 0.f};

    const int nsteps = K >> 6;
    for (int kt = 0; kt < nsteps; ++kt) {
        const int kbase = kt << 6;
#pragma unroll
        for (int c = 0; c < 4; ++c) {
            int chunk = wave * 4 + c;
            int gi = chunk * 64 + lane;
            int m  = gi >> 3;
            int cp = gi & 7;
            int g  = cp ^ (m & 7);
            stage16(A  + (size_t)(m0 + m) * ldk + kbase + g * 8, As + chunk * 512, lane);
            stage16(Bt + (size_t)(n0 + m) * ldk + kbase + g * 8, Bs + chunk * 512, lane);
        }
        __syncthreads();
#pragma unroll
        for (int ks = 0; ks < 2; ++ks) {
            bf16x8 af[4], bfr[4];
#pragma unroll
            for (int i = 0; i < 4; ++i) {
                int m = wm * 64 + i * 16 + l16;
                int g = ks * 4 + quad;
                af[i]  = *(const bf16x8*)(As + m * 64 + ((g ^ (m & 7)) * 8));
                int n = wn * 64 + i * 16 + l16;
                bfr[i] = *(const bf16x8*)(Bs + n * 64 + ((g ^ (n & 7)) * 8));
            }
#pragma unroll
            for (int i = 0; i < 4; ++i)
#pragma unroll
                for (int j = 0; j < 4; ++j)
                    acc[i][j] = __builtin_amdgcn_mfma_f32_16x16x32_bf16(af[i], bfr[j], acc[i][j], 0, 0, 0);
        }
        __syncthreads();
    }

    float* Cz = (EPI == 4) ? (z ? (float*)C2 : (float*)C) : nullptr;
#pragma unroll
    for (int i = 0; i < 4; ++i) {
        int row = m0 + wm * 64 + i * 16 + quad * 4;
#pragma unroll
        for (int j = 0; j < 4; ++j) {
            int col = n0 + wn * 64 + j * 16 + l16;
            float bv = (EPI == 2) ? bias[col] : 0.f;
#pragma unroll
            for (int r = 0; r < 4; ++r) {
                float v = acc[i][j][r];
                if (EPI == 2) v = gelu_exact(v + bv);
                size_t idx = (size_t)(row + r) * N + col;
                if (EPI == 4) Cz[idx] = v;
                else          ((bf16*)C)[idx] = (bf16)v;
            }
        }
    }
}

// ---------------- 256x256 8-wave 4-phase counted-vmcnt GEMM, v2 ----------------
// v2 fix vs R3: all K-loop LDS reads are inline-asm ds_read_b128 (compiler cannot
// see them alias the global_load_lds destinations -> no auto-inserted vmcnt(0)
// drains). Waits are fully manual: lgkmcnt(0)+sched_barrier(0) per phase (rule #18),
// one counted vmcnt per K-tile (never 0 in steady state).
// Staging schedule for tile t (buf p = t&1):
//   P1: ds A-sub0(8)+B-sub0(4); stage (t+1,A-hi)+(t+1,B-lo) [other buf]
//   P2: ds B-sub1(4);           stage (t+1,B-hi)            [other buf]
//   P3: ds A-sub1(8);           no stage
//   P4: no ds; stage (t+2,A-lo) [CURRENT buf A-lo: safe, all A reads done at P3 bar];
//       MFMA; vmcnt(2) (drain t+1's halves, keep t+2's A-lo in flight); bar
// EPI: 0 = bf16 raw; 2 = +bias,gelu bf16; 4 = fp32 partial to C[z].
template <int EPI>
__global__ __launch_bounds__(512, 2) void gemm256(const bf16* __restrict__ A,
                                                  const bf16* __restrict__ Bt,
                                                  void* __restrict__ C0, void* __restrict__ C1,
                                                  void* __restrict__ C2v, void* __restrict__ C3,
                                                  const float* __restrict__ bias,
                                                  int M, int N, int K, int ldk) {
    __shared__ __align__(16) bf16 As[2 * 16384];   // 64 KiB (2 bufs x 256x64)
    __shared__ __align__(16) bf16 Bs[2 * 16384];   // 64 KiB
    const int tid  = threadIdx.x;
    const int lane = tid & 63;
    const int wave = tid >> 6;     // 0..7
    const int l16  = lane & 15;
    const int quad = lane >> 4;
    const int wm = wave >> 2;      // 0..1
    const int wn = wave & 3;       // 0..3

    int bx, by, bz;
    {
        const int Gx = gridDim.x, Gy = gridDim.y, Gz = gridDim.z;
        const int nwg = Gx * Gy * Gz;
        int L = blockIdx.x + Gx * (blockIdx.y + Gy * blockIdx.z);
        if ((nwg & 7) == 0) {
            int chunk = nwg >> 3;
            L = (L & 7) * chunk + (L >> 3);
        }
        bx = L % Gx; int rest = L / Gx; by = rest % Gy; bz = rest / Gy;
    }
    const int m0 = by * 256, n0 = bx * 256;
    const int z  = bz;
    A  += (size_t)z * K;
    Bt += (size_t)z * K;

    // ---- staging geometry: half-tile = 128 rows x 64 cols of one operand, 2 slots.
    // slot s: gi = s*512 + tid; row = R0 + (gi>>3); stored granule = lane&7;
    // source granule = (lane&7) ^ (row&7)  (constant per thread: R0, s*64 are mult of 8)
    const int grow = wave * 8 + (lane >> 3);          // 0..63
    const int gg   = (lane & 7) ^ (grow & 7);
    const bf16* sA = A  + (size_t)(m0 + grow) * ldk + gg * 8;
    const bf16* sB = Bt + (size_t)(n0 + grow) * ldk + gg * 8;
    const int dchunk = wave * 512;                    // elements; + R0*64 + s*4096

    // ---- read geometry (byte offsets into buffer)
    const unsigned s7 = (unsigned)(l16 & 7);
    const unsigned e0 = ((unsigned)quad ^ s7) * 16;   // kk=0 granule; kk=1 = e0^64
    const unsigned arow0 = (unsigned)(wm * 128 + l16) * 128;
    const unsigned brow0 = (unsigned)(wn * 64 + l16) * 128;
    const unsigned asBase = lds_addr(As);
    const unsigned bsBase = lds_addr(Bs);

    f32x4 acc[8][4];
#pragma unroll
    for (int i = 0; i < 8; ++i)
#pragma unroll
        for (int j = 0; j < 4; ++j) acc[i][j] = (f32x4){0.f, 0.f, 0.f, 0.f};

    const int nt = K >> 6;

    auto stageHalf = [&](int t, int R0, bool isB) {
        const int kb = t << 6;
        const bf16* s = isB ? sB : sA;
        bf16* d = (isB ? Bs : As) + (t & 1) * 16384 + R0 * 64 + dchunk;
        stage16(s + (size_t)R0 * ldk + kb, d, lane);
        stage16(s + (size_t)(R0 + 64) * ldk + kb, d + 4096, lane);
    };

    // ---- prologue: tile0 fully staged + tile1 A-lo in flight
    stageHalf(0, 0, false); stageHalf(0, 128, false);
    stageHalf(0, 0, true);  stageHalf(0, 128, true);
    if (1 < nt) {
        stageHalf(1, 0, false);
        asm volatile("s_waitcnt vmcnt(2)");
    } else {
        asm volatile("s_waitcnt vmcnt(0)");
    }
    __builtin_amdgcn_s_barrier();

    for (int t = 0; t < nt; ++t) {
        const unsigned ab = asBase + (unsigned)(t & 1) * 32768 + arow0;
        const unsigned bb = bsBase + (unsigned)(t & 1) * 32768 + brow0;
        bf16x8 af[4][2], b0[2][2], b1[2][2];

        // ---- P1: ds A-sub0 + B-sub0 ; stage (t+1,A-hi)+(t+1,B-lo) ; MFMA q(0,0)
#pragma unroll
        for (int i = 0; i < 4; ++i) {
            af[i][0] = dsr(ab + i * 2048 + e0);
            af[i][1] = dsr(ab + i * 2048 + (e0 ^ 64));
        }
#pragma unroll
        for (int j = 0; j < 2; ++j) {
            b0[j][0] = dsr(bb + j * 2048 + e0);
            b0[j][1] = dsr(bb + j * 2048 + (e0 ^ 64));
        }
        if (t + 1 < nt) { stageHalf(t + 1, 128, false); stageHalf(t + 1, 0, true); }
        __builtin_amdgcn_s_barrier();
        asm volatile("s_waitcnt lgkmcnt(0)");
        __builtin_amdgcn_sched_barrier(0);
        __builtin_amdgcn_s_setprio(1);
#pragma unroll
        for (int i = 0; i < 4; ++i)
#pragma unroll
            for (int j = 0; j < 2; ++j)
#pragma unroll
                for (int kk = 0; kk < 2; ++kk)
                    acc[i][j] = __builtin_amdgcn_mfma_f32_16x16x32_bf16(af[i][kk], b0[j][kk], acc[i][j], 0, 0, 0);
        __builtin_amdgcn_s_setprio(0);
        __builtin_amdgcn_s_barrier();

        // ---- P2: ds B-sub1 ; stage (t+1,B-hi) ; MFMA q(0,1)
#pragma unroll
        for (int j = 0; j < 2; ++j) {
            b1[j][0] = dsr(bb + 4096 + j * 2048 + e0);
            b1[j][1] = dsr(bb + 4096 + j * 2048 + (e0 ^ 64));
        }
        if (t + 1 < nt) stageHalf(t + 1, 128, true);
        __builtin_amdgcn_s_barrier();
        asm volatile("s_waitcnt lgkmcnt(0)");
        __builtin_amdgcn_sched_barrier(0);
        __builtin_amdgcn_s_setprio(1);
#pragma unroll
        for (int i = 0; i < 4; ++i)
#pragma unroll
            for (int j = 0; j < 2; ++j)
#pragma unroll
                for (int kk = 0; kk < 2; ++kk)
                    acc[i][j + 2] = __builtin_amdgcn_mfma_f32_16x16x32_bf16(af[i][kk], b1[j][kk], acc[i][j + 2], 0, 0, 0);
        __builtin_amdgcn_s_setprio(0);
        __builtin_amdgcn_s_barrier();

        // ---- P3: ds A-sub1 (overwrite af) ; MFMA q(1,1)
#pragma unroll
        for (int i = 0; i < 4; ++i) {
            af[i][0] = dsr(ab + 8192 + i * 2048 + e0);
            af[i][1] = dsr(ab + 8192 + i * 2048 + (e0 ^ 64));
        }
        __builtin_amdgcn_s_barrier();
        asm volatile("s_waitcnt lgkmcnt(0)");
        __builtin_amdgcn_sched_barrier(0);
        __builtin_amdgcn_s_setprio(1);
#pragma unroll
        for (int i = 0; i < 4; ++i)
#pragma unroll
            for (int j = 0; j < 2; ++j)
#pragma unroll
                for (int kk = 0; kk < 2; ++kk)
                    acc[i + 4][j + 2] = __builtin_amdgcn_mfma_f32_16x16x32_bf16(af[i][kk], b1[j][kk], acc[i + 4][j + 2], 0, 0, 0);
        __builtin_amdgcn_s_setprio(0);
        __builtin_amdgcn_s_barrier();

        // ---- P4: stage (t+2,A-lo) into current buf ; MFMA q(1,0) ; counted vmcnt
        if (t + 2 < nt) stageHalf(t + 2, 0, false);
        __builtin_amdgcn_s_barrier();
        __builtin_amdgcn_s_setprio(1);
#pragma unroll
        for (int i = 0; i < 4; ++i)
#pragma unroll
            for (int j = 0; j < 2; ++j)
#pragma unroll
                for (int kk = 0; kk < 2; ++kk)
                    acc[i + 4][j] = __builtin_amdgcn_mfma_f32_16x16x32_bf16(af[i][kk], b0[j][kk], acc[i + 4][j], 0, 0, 0);
        __builtin_amdgcn_s_setprio(0);
        if (t + 2 < nt) { asm volatile("s_waitcnt vmcnt(2)"); }
        else            { asm volatile("s_waitcnt vmcnt(0)"); }
        __builtin_amdgcn_s_barrier();
    }

    // ---- epilogue ----
    float* Cz = nullptr;
    if (EPI == 4) Cz = (z == 0) ? (float*)C0 : (z == 1) ? (float*)C1 : (z == 2) ? (float*)C2v : (float*)C3;
#pragma unroll
    for (int i = 0; i < 8; ++i) {
        int row = m0 + wm * 128 + i * 16 + quad * 4;
#pragma unroll
        for (int j = 0; j < 4; ++j) {
            int col = n0 + wn * 64 + j * 16 + l16;
            float bv = (EPI == 2) ? bias[col] : 0.f;
#pragma unroll
            for (int r = 0; r < 4; ++r) {
                float v = acc[i][j][r];
                if (EPI == 2) v = gelu_exact(v + bv);
                size_t idx = (size_t)(row + r) * N + col;
                if (EPI == 4) Cz[idx] = v;
                else          ((bf16*)C0)[idx] = (bf16)v;
            }
        }
    }
}

// ---------------- flash attention (r11: 512-thread blocks + XCD swizzle) ----------------
__global__ __launch_bounds__(512, 4) void flash_attn(const bf16* __restrict__ qkv,
                                                     const unsigned long long* __restrict__ maskb,
                                                     bf16* __restrict__ o) {
    __shared__ __align__(16) bf16 Ks[128 * 64];    // swizzled packed [t][g^(t&7)]
    __shared__ __align__(16) bf16 Vts[64 * 136];   // [d][tc], tc = t-permuted, pad 8
    const int tid  = threadIdx.x;
    const int lane = tid & 63;
    const int wave = tid >> 6;      // 0..7
    const int l16  = lane & 15;
    const int quad = lane >> 4;

    int bqx, bhy;
    {
        const int Gx = gridDim.x, Gy = gridDim.y;
        int L = blockIdx.x + Gx * blockIdx.y;
        int chunk = (Gx * Gy) >> 3;
        L = (L & 7) * chunk + (L >> 3);
        bqx = L % Gx; bhy = L / Gx;
    }
    const int bh = bhy;
    const int b = bh >> 4, h = bh & 15;
    const int q0 = bqx * 128;
    const size_t rowb = (size_t)b * SS;
    const float SCL = 0.18033688011112042f;  // 0.125 * log2(e)

    const size_t qrow = (rowb + q0 + wave * 16 + l16) * 3072 + h * 64;
    bf16x8 qf[2];
    {
        bf16x8 q0r = *(const bf16x8*)(qkv + qrow + quad * 8);
        bf16x8 q1r = *(const bf16x8*)(qkv + qrow + 32 + quad * 8);
#pragma unroll
        for (int j = 0; j < 8; ++j) {
            qf[0][j] = (bf16)((float)q0r[j] * SCL);
            qf[1][j] = (bf16)((float)q1r[j] * SCL);
        }
    }

    f32x4 oacc[4];
#pragma unroll
    for (int d = 0; d < 4; ++d) oacc[d] = (f32x4){0.f, 0.f, 0.f, 0.f};
    f32x4 lacc = (f32x4){0.f, 0.f, 0.f, 0.f};
    const int mrow32 = (q0 + wave * 16 + l16) * 32;

    bf16x8 ones;
#pragma unroll
    for (int j = 0; j < 8; ++j) ones[j] = (bf16)1.0f;

    const int vt_tc = (lane >> 4) * 32 + ((lane >> 1) & 3) * 8 + ((lane >> 3) & 1) * 4 + 2 * (lane & 1);
    const int vd8 = wave * 8;

    int kst[2], ksg[2];
#pragma unroll
    for (int c = 0; c < 2; ++c) {
        int gi = (wave * 2 + c) * 64 + lane;
        kst[c] = gi >> 3;
        ksg[c] = (gi & 7) ^ (kst[c] & 7);
    }

    bf16x8 kreg[2], vreg[2];
    ulonglong2 mwreg;
#pragma unroll
    for (int c = 0; c < 2; ++c)
        kreg[c] = *(const bf16x8*)(qkv + (rowb + kst[c]) * 3072 + 1024 + h * 64 + ksg[c] * 8);
    {
        const bf16* vg = qkv + (rowb + 2 * lane) * 3072 + 2048 + h * 64 + vd8;
        vreg[0] = *(const bf16x8*)(vg);
        vreg[1] = *(const bf16x8*)(vg + 3072);
    }
    mwreg = *(const ulonglong2*)(maskb + mrow32);

    for (int kt = 0; kt < SS / 128; ++kt) {
        __syncthreads();
#pragma unroll
        for (int c = 0; c < 2; ++c)
            *(bf16x8*)(Ks + (wave * 2 + c) * 512 + lane * 8) = kreg[c];
#pragma unroll
        for (int j = 0; j < 8; ++j) {
            bf16x2 pr; pr[0] = vreg[0][j]; pr[1] = vreg[1][j];
            *(bf16x2*)(Vts + (vd8 + j) * 136 + vt_tc) = pr;
        }
        ulonglong2 mw = mwreg;
        __syncthreads();

        if (kt + 1 < SS / 128) {
            const int t0n = (kt + 1) * 128;
#pragma unroll
            for (int c = 0; c < 2; ++c)
                kreg[c] = *(const bf16x8*)(qkv + (rowb + t0n + kst[c]) * 3072 + 1024 + h * 64 + ksg[c] * 8);
            {
                const bf16* vg = qkv + (rowb + t0n + 2 * lane) * 3072 + 2048 + h * 64 + vd8;
                vreg[0] = *(const bf16x8*)(vg);
                vreg[1] = *(const bf16x8*)(vg + 3072);
            }
            mwreg = *(const ulonglong2*)(maskb + mrow32 + (kt + 1) * 2);
        }

        f32x4 st[8];
        __builtin_amdgcn_s_setprio(1);
#pragma unroll
        for (int tg = 0; tg < 8; ++tg) {
            int tl = tg * 16 + l16;
            bf16x8 a0 = *(const bf16x8*)(Ks + tl * 64 + ((quad       ^ (tl & 7)) * 8));
            bf16x8 a1 = *(const bf16x8*)(Ks + tl * 64 + (((4 + quad) ^ (tl & 7)) * 8));
            f32x4 s = (f32x4){0.f, 0.f, 0.f, 0.f};
            s = __builtin_amdgcn_mfma_f32_16x16x32_bf16(a0, qf[0], s, 0, 0, 0);
            s = __builtin_amdgcn_mfma_f32_16x16x32_bf16(a1, qf[1], s, 0, 0, 0);
            st[tg] = s;
        }
        __builtin_amdgcn_s_setprio(0);

        unsigned long long s0 = mw.x >> (quad * 4);
        unsigned long long s1 = mw.y >> (quad * 4);
        bf16x8 pva[4];
#pragma unroll
        for (int tg = 0; tg < 8; ++tg) {
            unsigned int bits = (unsigned int)(((tg < 4) ? s0 : s1) >> ((tg & 3) * 16));
#pragma unroll
            for (int r = 0; r < 4; ++r) {
                float p = __builtin_amdgcn_exp2f(st[tg][r]);
                p = ((bits >> r) & 1u) ? 0.f : p;
                pva[tg >> 1][(tg & 1) * 4 + r] = (bf16)p;
            }
        }

        __builtin_amdgcn_s_setprio(1);
#pragma unroll
        for (int kc = 0; kc < 4; ++kc) {
#pragma unroll
            for (int dg = 0; dg < 4; ++dg) {
                bf16x8 bfrag = *(const bf16x8*)(Vts + (dg * 16 + l16) * 136 + kc * 32 + quad * 8);
                oacc[dg] = __builtin_amdgcn_mfma_f32_16x16x32_bf16(pva[kc], bfrag, oacc[dg], 0, 0, 0);
            }
            lacc = __builtin_amdgcn_mfma_f32_16x16x32_bf16(pva[kc], ones, lacc, 0, 0, 0);
        }
        __builtin_amdgcn_s_setprio(0);
    }

#pragma unroll
    for (int r = 0; r < 4; ++r) {
        float inv_l = 1.f / lacc[r];
        bf16* orow = o + (rowb + q0 + wave * 16 + quad * 4 + r) * DD + h * 64;
#pragma unroll
        for (int dg = 0; dg < 4; ++dg)
            orow[dg * 16 + l16] = (bf16)(oacc[dg][r] * inv_l);
    }
}

// ---------------- fused split-K reduce + bias (+gelu) + residual LayerNorm ----------------
template <bool GELU, bool WB16, int NP>
__global__ __launch_bounds__(256) void ln_fused(const float* __restrict__ resid,
                                                const float* __restrict__ p0,
                                                const float* __restrict__ p1,
                                                const float* __restrict__ p2,
                                                const float* __restrict__ p3,
                                                const float* __restrict__ bias,
                                                const float* __restrict__ g,
                                                const float* __restrict__ bb,
                                                float* __restrict__ outf,
                                                bf16* __restrict__ outb) {
    const int row = blockIdx.x;
    const int tid = threadIdx.x;
    const size_t base = (size_t)row * DD + tid * 4;
    float4 a0 = *(const float4*)(p0 + base);
    float4 a1 = *(const float4*)(p1 + base);
    float4 bz = *(const float4*)(bias + tid * 4);
    float ax = a0.x + a1.x + bz.x;
    float ay = a0.y + a1.y + bz.y;
    float az = a0.z + a1.z + bz.z;
    float aw = a0.w + a1.w + bz.w;
    if (NP == 4) {
        float4 a2 = *(const float4*)(p2 + base);
        float4 a3 = *(const float4*)(p3 + base);
        ax += a2.x + a3.x; ay += a2.y + a3.y; az += a2.z + a3.z; aw += a2.w + a3.w;
    }
    if (GELU) { ax = gelu_exact(ax); ay = gelu_exact(ay); az = gelu_exact(az); aw = gelu_exact(aw); }
    float s1 = ax + ay + az + aw;
    float s2 = ax * ax + ay * ay + az * az + aw * aw;
#pragma unroll
    for (int off = 32; off; off >>= 1) {
        s1 += __shfl_xor(s1, off, 64);
        s2 += __shfl_xor(s2, off, 64);
    }
    __shared__ float red[8];
    if ((tid & 63) == 0) { red[(tid >> 6) * 2] = s1; red[(tid >> 6) * 2 + 1] = s2; }
    __syncthreads();
    s1 = red[0] + red[2] + red[4] + red[6];
    s2 = red[1] + red[3] + red[5] + red[7];
    float mean = s1 * (1.f / DD);
    float var  = s2 * (1.f / DD) - mean * mean;
    float rs = rsqrtf(var + 1e-5f);
    float4 gv = *(const float4*)(g + tid * 4);
    float4 bv = *(const float4*)(bb + tid * 4);
    float4 rv = *(const float4*)(resid + base);
    float y0 = rv.x + (ax - mean) * rs * gv.x + bv.x;
    float y1 = rv.y + (ay - mean) * rs * gv.y + bv.y;
    float y2 = rv.z + (az - mean) * rs * gv.z + bv.z;
    float y3 = rv.w + (aw - mean) * rs * gv.w + bv.w;
    float4 yo = make_float4(y0, y1, y2, y3);
    *(float4*)(outf + base) = yo;
    if (WB16) {
        bf16x4 ob;
        ob[0] = (bf16)y0; ob[1] = (bf16)y1; ob[2] = (bf16)y2; ob[3] = (bf16)y3;
        *(bf16x4*)(outb + base) = ob;
    }
}

// ---------------- launcher ----------------
extern "C" void kernel_launch(void* const* d_in, const int* in_sizes, int n_in,
                              void* d_out, int out_size, void* d_ws, size_t ws_size,
                              hipStream_t stream) {
    const float* x    = (const float*)d_in[0];
    const int*   mask = (const int*)d_in[1];
    const float* Wq   = (const float*)d_in[2];
    const float* Wk   = (const float*)d_in[3];
    const float* Wv   = (const float*)d_in[4];
    const float* Wo   = (const float*)d_in[5];
    const float* bo   = (const float*)d_in[6];
    const float* ln1g = (const float*)d_in[7];
    const float* ln1b = (const float*)d_in[8];
    const float* W1   = (const float*)d_in[9];
    const float* b1   = (const float*)d_in[10];
    const float* W2   = (const float*)d_in[11];
    const float* b2   = (const float*)d_in[12];
    const float* ln2g = (const float*)d_in[13];
    const float* ln2b = (const float*)d_in[14];

    char* w = (char*)d_ws;
    bf16* Wqkv_t = (bf16*)w; w += (size_t)3072 * 1024 * 2;   // 6 MB
    bf16* Wo_t   = (bf16*)w; w += (size_t)1024 * 1024 * 2;   // 2 MB
    bf16* W1_t   = (bf16*)w; w += (size_t)4096 * 1024 * 2;   // 8 MB
    bf16* W2_t   = (bf16*)w; w += (size_t)1024 * 4096 * 2;   // 8 MB
    bf16* x_b    = (bf16*)w; w += (size_t)MROWS * DD * 2;    // 8 MB (then o_b, x1_b, FFN2 fp1)
    bf16* qkv    = (bf16*)w; w += (size_t)MROWS * 3072 * 2;  // 24 MB (then FFN2 fp1 tail / fp2)
    float* R     = (float*)w; w += (size_t)MROWS * DD * 8;   // 32 MB (O-proj p0/p1, then h_b)
    float* x1_f  = (float*)w; w += (size_t)MROWS * DD * 4;   // 16 MB
    unsigned long long* maskb = (unsigned long long*)w; w += (size_t)SS * 32 * 8;  // 0.5 MB
    bf16* o_b  = x_b;                 // alive: attention -> O-proj
    bf16* x1_b = x_b;                 // alive: LN1 -> FFN1
    float* op0 = R;                   // O-proj partial z=0
    float* op1 = R + (size_t)MROWS * DD;  // O-proj partial z=1
    bf16*  h_b = (bf16*)R;            // FFN1 out (32 MB; partials dead by then)
    // FFN2 split-4 fp32 partials (16 MB each), all regions dead by FFN2 time:
    float* fp0 = (float*)d_out;                            // reduced in-place by LN2
    float* fp1 = (float*)x_b;                              // x_b (8 MB) + qkv head (8 MB)
    float* fp2 = (float*)x_b + (size_t)4 * 1024 * 1024;    // qkv tail (16 MB)
    float* fp3 = (float*)d_ws;                             // Wqkv_t+Wo_t+W1_t (16 MB, dead after FFN1)

    // fused prep (one launch)
    prep_kernel<<<32768, 256, 0, stream>>>(x, x_b, mask, maskb,
                                           Wq, Wk, Wv, Wo, W1, W2,
                                           Wqkv_t, Wo_t, W1_t, W2_t);

    // QKV projection: [4096,1024] x [1024,3072] -> qkv bf16  (256^2 counted-vmcnt)
    gemm256<0><<<dim3(12, 16, 1), 512, 0, stream>>>(x_b, Wqkv_t, qkv, nullptr, nullptr, nullptr, nullptr, MROWS, 3072, 1024, 1024);
    // attention (512-thread blocks, 128 q-rows each)
    flash_attn<<<dim3(SS / 128, BB * HH), 512, 0, stream>>>(qkv, maskb, o_b);
    // O-proj, split-K=2 -> fp32 partials (bias deferred to LN1)
    gemm_bt<4><<<dim3(8, 32, 2), 256, 0, stream>>>(o_b, Wo_t, op0, op1, nullptr, MROWS, 1024, 512, 1024);
    // x1 = x + LN(op0+op1+bo)
    ln_fused<false, true, 2><<<MROWS, 256, 0, stream>>>(x, op0, op1, nullptr, nullptr, bo, ln1g, ln1b, x1_f, x1_b);
    // FFN1: gelu(x1@W1 + b1) -> bf16  (256^2 counted-vmcnt)
    gemm256<2><<<dim3(16, 16, 1), 512, 0, stream>>>(x1_b, W1_t, h_b, nullptr, nullptr, nullptr, b1, MROWS, 4096, 1024, 1024);
    // FFN2, split-K=4 -> fp32 partials (bias+gelu deferred to LN2)  (256^2 counted-vmcnt)
    gemm256<4><<<dim3(4, 16, 4), 512, 0, stream>>>(h_b, W2_t, fp0, fp1, fp2, fp3, nullptr, MROWS, 1024, 1024, 4096);
    // out = x1 + LN(gelu(fp0+fp1+fp2+fp3+b2))  (fp32, in-place on d_out)
    ln_fused<true, false, 4><<<MROWS, 256, 0, stream>>>(x1_f, fp0, fp1, fp2, fp3, b2, ln2g, ln2b, (float*)d_out, nullptr);
}

// Round 6
// 369.404 us; speedup vs baseline: 1.1856x; 1.0067x over previous
//
#include <hip/hip_runtime.h>
#include <hip/hip_bf16.h>
#include <cstdint>

// Problem constants
#define BB 2
#define SS 2048
#define DD 1024
#define HH 16
#define HDIM 64
#define MROWS (BB*SS)   // 4096

typedef __bf16 bf16;
using bf16x8 = __bf16 __attribute__((ext_vector_type(8)));
using bf16x4 = __bf16 __attribute__((ext_vector_type(4)));
using bf16x2 = __bf16 __attribute__((ext_vector_type(2)));
using f32x4  = float __attribute__((ext_vector_type(4)));

__device__ __forceinline__ float gelu_exact(float x) {
    return 0.5f * x * (1.f + erff(x * 0.70710678118654752f));
}

// global->LDS direct DMA, 16B per lane (lane i deposits at base + i*16).
__device__ __forceinline__ void stage16(const bf16* g, bf16* lds_chunk_base, int lane) {
#if __has_builtin(__builtin_amdgcn_global_load_lds)
    __builtin_amdgcn_global_load_lds((const __attribute__((address_space(1))) void*)g,
                                     (__attribute__((address_space(3))) void*)lds_chunk_base,
                                     16, 0, 0);
#else
    *(bf16x8*)(lds_chunk_base + lane * 8) = *(const bf16x8*)g;
#endif
}

// 32-bit LDS byte address for inline-asm DS ops
__device__ __forceinline__ unsigned lds_addr(const void* p) {
    return (unsigned)(uintptr_t)(const __attribute__((address_space(3))) void*)p;
}

// inline-asm ds_read_b128: invisible to the compiler's waitcnt pass, so in-flight
// global_load_lds staging is NOT drained before it (the R3 failure mode).
__device__ __forceinline__ bf16x8 dsr(unsigned addr) {
    bf16x8 r;
    asm volatile("ds_read_b128 %0, %1" : "=v"(r) : "v"(addr));
    return r;
}

// ---------------- fused prep: cast x, pack mask, transpose all weights ----------------
__global__ __launch_bounds__(256) void prep_kernel(
    const float* __restrict__ x, bf16* __restrict__ x_b,
    const int* __restrict__ mask, unsigned long long* __restrict__ maskb,
    const float* __restrict__ Wq, const float* __restrict__ Wk,
    const float* __restrict__ Wv, const float* __restrict__ Wo,
    const float* __restrict__ W1, const float* __restrict__ W2,
    bf16* __restrict__ Wqkv_t, bf16* __restrict__ Wo_t,
    bf16* __restrict__ W1_t, bf16* __restrict__ W2_t) {
    const int bid = blockIdx.x;
    if (bid < 4096) {
        int i = bid * 256 + threadIdx.x;
        float4 v = ((const float4*)x)[i];
        bf16x4 o;
        o[0] = (bf16)v.x; o[1] = (bf16)v.y; o[2] = (bf16)v.z; o[3] = (bf16)v.w;
        *(bf16x4*)(x_b + (size_t)i * 4) = o;
        return;
    }
    if (bid < 20480) {
        int gid = (bid - 4096) * 256 + threadIdx.x;
        int mv = mask[gid];
        unsigned long long bal = __ballot(mv == 1);
        if ((threadIdx.x & 63) == 0) maskb[gid >> 6] = bal;
        return;
    }
    int t = bid - 20480;
    const float* W; bf16* Wt; int K, N, bx, by;
    if (t < 4096) {
        int wsel = t >> 10;
        int tt = t & 1023;
        W  = (wsel == 0) ? Wq : (wsel == 1) ? Wk : (wsel == 2) ? Wv : Wo;
        Wt = (wsel == 3) ? Wo_t : (Wqkv_t + (size_t)wsel * 1024 * 1024);
        K = 1024; N = 1024; bx = (tt & 31) * 32; by = (tt >> 5) * 32;
    } else if (t < 8192) {
        int tt = t - 4096;
        W = W1; Wt = W1_t; K = 1024; N = 4096;
        bx = (tt & 127) * 32; by = (tt >> 7) * 32;
    } else {
        int tt = t - 8192;
        W = W2; Wt = W2_t; K = 4096; N = 1024;
        bx = (tt & 31) * 32; by = (tt >> 5) * 32;
    }
    __shared__ float tile[32][33];
    int tx = threadIdx.x & 31;
    int ty = threadIdx.x >> 5;
#pragma unroll
    for (int j = 0; j < 4; ++j)
        tile[ty + j * 8][tx] = W[(size_t)(by + ty + j * 8) * N + bx + tx];
    __syncthreads();
#pragma unroll
    for (int j = 0; j < 4; ++j)
        Wt[(size_t)(bx + ty + j * 8) * K + by + tx] = (bf16)tile[tx][ty + j * 8];
}

// ---------------- bf16 MFMA GEMM: 128x128 tile (O-proj only) ----------------
// launch_bounds (256,2): O-proj runs 512 blocks = 2 blocks/CU; the old 3-block
// register cap (170 VGPR) bought nothing.
template <int EPI>
__global__ __launch_bounds__(256, 2) void gemm_bt(const bf16* __restrict__ A,
                                                  const bf16* __restrict__ Bt,
                                                  void* __restrict__ C,
                                                  void* __restrict__ C2,
                                                  const float* __restrict__ bias,
                                                  int M, int N, int K, int ldk) {
    __shared__ __align__(16) bf16 As[128 * 64];
    __shared__ __align__(16) bf16 Bs[128 * 64];
    const int tid  = threadIdx.x;
    const int lane = tid & 63;
    const int wave = tid >> 6;
    const int l16  = lane & 15;
    const int quad = lane >> 4;
    const int wm = wave >> 1, wn = wave & 1;

    int bx, by, bz;
    {
        const int Gx = gridDim.x, Gy = gridDim.y, Gz = gridDim.z;
        const int nwg = Gx * Gy * Gz;
        int L = blockIdx.x + Gx * (blockIdx.y + Gy * blockIdx.z);
        if ((nwg & 7) == 0) {
            int chunk = nwg >> 3;
            L = (L & 7) * chunk + (L >> 3);
        }
        bx = L % Gx; int rest = L / Gx; by = rest % Gy; bz = rest / Gy;
    }
    const int m0 = by * 128, n0 = bx * 128;
    const int z  = bz;
    A  += (size_t)z * K;
    Bt += (size_t)z * K;

    f32x4 acc[4][4];
#pragma unroll
    for (int i = 0; i < 4; ++i)
#pragma unroll
        for (int j = 0; j < 4; ++j) acc[i][j] = (f32x4){0.f, 0.f, 0.f, 0.f};

    const int nsteps = K >> 6;
    for (int kt = 0; kt < nsteps; ++kt) {
        const int kbase = kt << 6;
#pragma unroll
        for (int c = 0; c < 4; ++c) {
            int chunk = wave * 4 + c;
            int gi = chunk * 64 + lane;
            int m  = gi >> 3;
            int cp = gi & 7;
            int g  = cp ^ (m & 7);
            stage16(A  + (size_t)(m0 + m) * ldk + kbase + g * 8, As + chunk * 512, lane);
            stage16(Bt + (size_t)(n0 + m) * ldk + kbase + g * 8, Bs + chunk * 512, lane);
        }
        __syncthreads();
#pragma unroll
        for (int ks = 0; ks < 2; ++ks) {
            bf16x8 af[4], bfr[4];
#pragma unroll
            for (int i = 0; i < 4; ++i) {
                int m = wm * 64 + i * 16 + l16;
                int g = ks * 4 + quad;
                af[i]  = *(const bf16x8*)(As + m * 64 + ((g ^ (m & 7)) * 8));
                int n = wn * 64 + i * 16 + l16;
                bfr[i] = *(const bf16x8*)(Bs + n * 64 + ((g ^ (n & 7)) * 8));
            }
#pragma unroll
            for (int i = 0; i < 4; ++i)
#pragma unroll
                for (int j = 0; j < 4; ++j)
                    acc[i][j] = __builtin_amdgcn_mfma_f32_16x16x32_bf16(af[i], bfr[j], acc[i][j], 0, 0, 0);
        }
        __syncthreads();
    }

    float* Cz = (EPI == 4) ? (z ? (float*)C2 : (float*)C) : nullptr;
#pragma unroll
    for (int i = 0; i < 4; ++i) {
        int row = m0 + wm * 64 + i * 16 + quad * 4;
#pragma unroll
        for (int j = 0; j < 4; ++j) {
            int col = n0 + wn * 64 + j * 16 + l16;
            float bv = (EPI == 2) ? bias[col] : 0.f;
#pragma unroll
            for (int r = 0; r < 4; ++r) {
                float v = acc[i][j][r];
                if (EPI == 2) v = gelu_exact(v + bv);
                size_t idx = (size_t)(row + r) * N + col;
                if (EPI == 4) Cz[idx] = v;
                else          ((bf16*)C)[idx] = (bf16)v;
            }
        }
    }
}

// ---------------- 256x256 8-wave 4-phase counted-vmcnt GEMM, v2 (unchanged from R5) ----------------
template <int EPI>
__global__ __launch_bounds__(512, 2) void gemm256(const bf16* __restrict__ A,
                                                  const bf16* __restrict__ Bt,
                                                  void* __restrict__ C0, void* __restrict__ C1,
                                                  void* __restrict__ C2v, void* __restrict__ C3,
                                                  const float* __restrict__ bias,
                                                  int M, int N, int K, int ldk) {
    __shared__ __align__(16) bf16 As[2 * 16384];   // 64 KiB (2 bufs x 256x64)
    __shared__ __align__(16) bf16 Bs[2 * 16384];   // 64 KiB
    const int tid  = threadIdx.x;
    const int lane = tid & 63;
    const int wave = tid >> 6;     // 0..7
    const int l16  = lane & 15;
    const int quad = lane >> 4;
    const int wm = wave >> 2;      // 0..1
    const int wn = wave & 3;       // 0..3

    int bx, by, bz;
    {
        const int Gx = gridDim.x, Gy = gridDim.y, Gz = gridDim.z;
        const int nwg = Gx * Gy * Gz;
        int L = blockIdx.x + Gx * (blockIdx.y + Gy * blockIdx.z);
        if ((nwg & 7) == 0) {
            int chunk = nwg >> 3;
            L = (L & 7) * chunk + (L >> 3);
        }
        bx = L % Gx; int rest = L / Gx; by = rest % Gy; bz = rest / Gy;
    }
    const int m0 = by * 256, n0 = bx * 256;
    const int z  = bz;
    A  += (size_t)z * K;
    Bt += (size_t)z * K;

    const int grow = wave * 8 + (lane >> 3);          // 0..63
    const int gg   = (lane & 7) ^ (grow & 7);
    const bf16* sA = A  + (size_t)(m0 + grow) * ldk + gg * 8;
    const bf16* sB = Bt + (size_t)(n0 + grow) * ldk + gg * 8;
    const int dchunk = wave * 512;                    // elements; + R0*64 + s*4096

    const unsigned s7 = (unsigned)(l16 & 7);
    const unsigned e0 = ((unsigned)quad ^ s7) * 16;   // kk=0 granule; kk=1 = e0^64
    const unsigned arow0 = (unsigned)(wm * 128 + l16) * 128;
    const unsigned brow0 = (unsigned)(wn * 64 + l16) * 128;
    const unsigned asBase = lds_addr(As);
    const unsigned bsBase = lds_addr(Bs);

    f32x4 acc[8][4];
#pragma unroll
    for (int i = 0; i < 8; ++i)
#pragma unroll
        for (int j = 0; j < 4; ++j) acc[i][j] = (f32x4){0.f, 0.f, 0.f, 0.f};

    const int nt = K >> 6;

    auto stageHalf = [&](int t, int R0, bool isB) {
        const int kb = t << 6;
        const bf16* s = isB ? sB : sA;
        bf16* d = (isB ? Bs : As) + (t & 1) * 16384 + R0 * 64 + dchunk;
        stage16(s + (size_t)R0 * ldk + kb, d, lane);
        stage16(s + (size_t)(R0 + 64) * ldk + kb, d + 4096, lane);
    };

    stageHalf(0, 0, false); stageHalf(0, 128, false);
    stageHalf(0, 0, true);  stageHalf(0, 128, true);
    if (1 < nt) {
        stageHalf(1, 0, false);
        asm volatile("s_waitcnt vmcnt(2)");
    } else {
        asm volatile("s_waitcnt vmcnt(0)");
    }
    __builtin_amdgcn_s_barrier();

    for (int t = 0; t < nt; ++t) {
        const unsigned ab = asBase + (unsigned)(t & 1) * 32768 + arow0;
        const unsigned bb = bsBase + (unsigned)(t & 1) * 32768 + brow0;
        bf16x8 af[4][2], b0[2][2], b1[2][2];

        // ---- P1
#pragma unroll
        for (int i = 0; i < 4; ++i) {
            af[i][0] = dsr(ab + i * 2048 + e0);
            af[i][1] = dsr(ab + i * 2048 + (e0 ^ 64));
        }
#pragma unroll
        for (int j = 0; j < 2; ++j) {
            b0[j][0] = dsr(bb + j * 2048 + e0);
            b0[j][1] = dsr(bb + j * 2048 + (e0 ^ 64));
        }
        if (t + 1 < nt) { stageHalf(t + 1, 128, false); stageHalf(t + 1, 0, true); }
        __builtin_amdgcn_s_barrier();
        asm volatile("s_waitcnt lgkmcnt(0)");
        __builtin_amdgcn_sched_barrier(0);
        __builtin_amdgcn_s_setprio(1);
#pragma unroll
        for (int i = 0; i < 4; ++i)
#pragma unroll
            for (int j = 0; j < 2; ++j)
#pragma unroll
                for (int kk = 0; kk < 2; ++kk)
                    acc[i][j] = __builtin_amdgcn_mfma_f32_16x16x32_bf16(af[i][kk], b0[j][kk], acc[i][j], 0, 0, 0);
        __builtin_amdgcn_s_setprio(0);
        __builtin_amdgcn_s_barrier();

        // ---- P2
#pragma unroll
        for (int j = 0; j < 2; ++j) {
            b1[j][0] = dsr(bb + 4096 + j * 2048 + e0);
            b1[j][1] = dsr(bb + 4096 + j * 2048 + (e0 ^ 64));
        }
        if (t + 1 < nt) stageHalf(t + 1, 128, true);
        __builtin_amdgcn_s_barrier();
        asm volatile("s_waitcnt lgkmcnt(0)");
        __builtin_amdgcn_sched_barrier(0);
        __builtin_amdgcn_s_setprio(1);
#pragma unroll
        for (int i = 0; i < 4; ++i)
#pragma unroll
            for (int j = 0; j < 2; ++j)
#pragma unroll
                for (int kk = 0; kk < 2; ++kk)
                    acc[i][j + 2] = __builtin_amdgcn_mfma_f32_16x16x32_bf16(af[i][kk], b1[j][kk], acc[i][j + 2], 0, 0, 0);
        __builtin_amdgcn_s_setprio(0);
        __builtin_amdgcn_s_barrier();

        // ---- P3
#pragma unroll
        for (int i = 0; i < 4; ++i) {
            af[i][0] = dsr(ab + 8192 + i * 2048 + e0);
            af[i][1] = dsr(ab + 8192 + i * 2048 + (e0 ^ 64));
        }
        __builtin_amdgcn_s_barrier();
        asm volatile("s_waitcnt lgkmcnt(0)");
        __builtin_amdgcn_sched_barrier(0);
        __builtin_amdgcn_s_setprio(1);
#pragma unroll
        for (int i = 0; i < 4; ++i)
#pragma unroll
            for (int j = 0; j < 2; ++j)
#pragma unroll
                for (int kk = 0; kk < 2; ++kk)
                    acc[i + 4][j + 2] = __builtin_amdgcn_mfma_f32_16x16x32_bf16(af[i][kk], b1[j][kk], acc[i + 4][j + 2], 0, 0, 0);
        __builtin_amdgcn_s_setprio(0);
        __builtin_amdgcn_s_barrier();

        // ---- P4
        if (t + 2 < nt) stageHalf(t + 2, 0, false);
        __builtin_amdgcn_s_barrier();
        __builtin_amdgcn_s_setprio(1);
#pragma unroll
        for (int i = 0; i < 4; ++i)
#pragma unroll
            for (int j = 0; j < 2; ++j)
#pragma unroll
                for (int kk = 0; kk < 2; ++kk)
                    acc[i + 4][j] = __builtin_amdgcn_mfma_f32_16x16x32_bf16(af[i][kk], b0[j][kk], acc[i + 4][j], 0, 0, 0);
        __builtin_amdgcn_s_setprio(0);
        if (t + 2 < nt) { asm volatile("s_waitcnt vmcnt(2)"); }
        else            { asm volatile("s_waitcnt vmcnt(0)"); }
        __builtin_amdgcn_s_barrier();
    }

    float* Cz = nullptr;
    if (EPI == 4) Cz = (z == 0) ? (float*)C0 : (z == 1) ? (float*)C1 : (z == 2) ? (float*)C2v : (float*)C3;
#pragma unroll
    for (int i = 0; i < 8; ++i) {
        int row = m0 + wm * 128 + i * 16 + quad * 4;
#pragma unroll
        for (int j = 0; j < 4; ++j) {
            int col = n0 + wn * 64 + j * 16 + l16;
            float bv = (EPI == 2) ? bias[col] : 0.f;
#pragma unroll
            for (int r = 0; r < 4; ++r) {
                float v = acc[i][j][r];
                if (EPI == 2) v = gelu_exact(v + bv);
                size_t idx = (size_t)(row + r) * N + col;
                if (EPI == 4) Cz[idx] = v;
                else          ((bf16*)C0)[idx] = (bf16)v;
            }
        }
    }
}

// ---------------- flash attention (r12: launch_bounds (512,2) — unleash VGPRs) ----------------
// Grid is 512 blocks = exactly 2 blocks/CU; the old (512,4) bound capped VGPRs at 64
// for a residency level that can never materialize. (512,2) -> 128-VGPR budget at the
// same achievable occupancy; compiler can keep st[8]/pva live instead of rematerializing.
__global__ __launch_bounds__(512, 2) void flash_attn(const bf16* __restrict__ qkv,
                                                     const unsigned long long* __restrict__ maskb,
                                                     bf16* __restrict__ o) {
    __shared__ __align__(16) bf16 Ks[128 * 64];    // swizzled packed [t][g^(t&7)]
    __shared__ __align__(16) bf16 Vts[64 * 136];   // [d][tc], tc = t-permuted, pad 8
    const int tid  = threadIdx.x;
    const int lane = tid & 63;
    const int wave = tid >> 6;      // 0..7
    const int l16  = lane & 15;
    const int quad = lane >> 4;

    int bqx, bhy;
    {
        const int Gx = gridDim.x, Gy = gridDim.y;
        int L = blockIdx.x + Gx * blockIdx.y;
        int chunk = (Gx * Gy) >> 3;
        L = (L & 7) * chunk + (L >> 3);
        bqx = L % Gx; bhy = L / Gx;
    }
    const int bh = bhy;
    const int b = bh >> 4, h = bh & 15;
    const int q0 = bqx * 128;
    const size_t rowb = (size_t)b * SS;
    const float SCL = 0.18033688011112042f;  // 0.125 * log2(e)

    const size_t qrow = (rowb + q0 + wave * 16 + l16) * 3072 + h * 64;
    bf16x8 qf[2];
    {
        bf16x8 q0r = *(const bf16x8*)(qkv + qrow + quad * 8);
        bf16x8 q1r = *(const bf16x8*)(qkv + qrow + 32 + quad * 8);
#pragma unroll
        for (int j = 0; j < 8; ++j) {
            qf[0][j] = (bf16)((float)q0r[j] * SCL);
            qf[1][j] = (bf16)((float)q1r[j] * SCL);
        }
    }

    f32x4 oacc[4];
#pragma unroll
    for (int d = 0; d < 4; ++d) oacc[d] = (f32x4){0.f, 0.f, 0.f, 0.f};
    f32x4 lacc = (f32x4){0.f, 0.f, 0.f, 0.f};
    const int mrow32 = (q0 + wave * 16 + l16) * 32;

    bf16x8 ones;
#pragma unroll
    for (int j = 0; j < 8; ++j) ones[j] = (bf16)1.0f;

    const int vt_tc = (lane >> 4) * 32 + ((lane >> 1) & 3) * 8 + ((lane >> 3) & 1) * 4 + 2 * (lane & 1);
    const int vd8 = wave * 8;

    int kst[2], ksg[2];
#pragma unroll
    for (int c = 0; c < 2; ++c) {
        int gi = (wave * 2 + c) * 64 + lane;
        kst[c] = gi >> 3;
        ksg[c] = (gi & 7) ^ (kst[c] & 7);
    }

    bf16x8 kreg[2], vreg[2];
    ulonglong2 mwreg;
#pragma unroll
    for (int c = 0; c < 2; ++c)
        kreg[c] = *(const bf16x8*)(qkv + (rowb + kst[c]) * 3072 + 1024 + h * 64 + ksg[c] * 8);
    {
        const bf16* vg = qkv + (rowb + 2 * lane) * 3072 + 2048 + h * 64 + vd8;
        vreg[0] = *(const bf16x8*)(vg);
        vreg[1] = *(const bf16x8*)(vg + 3072);
    }
    mwreg = *(const ulonglong2*)(maskb + mrow32);

    for (int kt = 0; kt < SS / 128; ++kt) {
        __syncthreads();
#pragma unroll
        for (int c = 0; c < 2; ++c)
            *(bf16x8*)(Ks + (wave * 2 + c) * 512 + lane * 8) = kreg[c];
#pragma unroll
        for (int j = 0; j < 8; ++j) {
            bf16x2 pr; pr[0] = vreg[0][j]; pr[1] = vreg[1][j];
            *(bf16x2*)(Vts + (vd8 + j) * 136 + vt_tc) = pr;
        }
        ulonglong2 mw = mwreg;
        __syncthreads();

        if (kt + 1 < SS / 128) {
            const int t0n = (kt + 1) * 128;
#pragma unroll
            for (int c = 0; c < 2; ++c)
                kreg[c] = *(const bf16x8*)(qkv + (rowb + t0n + kst[c]) * 3072 + 1024 + h * 64 + ksg[c] * 8);
            {
                const bf16* vg = qkv + (rowb + t0n + 2 * lane) * 3072 + 2048 + h * 64 + vd8;
                vreg[0] = *(const bf16x8*)(vg);
                vreg[1] = *(const bf16x8*)(vg + 3072);
            }
            mwreg = *(const ulonglong2*)(maskb + mrow32 + (kt + 1) * 2);
        }

        f32x4 st[8];
        __builtin_amdgcn_s_setprio(1);
#pragma unroll
        for (int tg = 0; tg < 8; ++tg) {
            int tl = tg * 16 + l16;
            bf16x8 a0 = *(const bf16x8*)(Ks + tl * 64 + ((quad       ^ (tl & 7)) * 8));
            bf16x8 a1 = *(const bf16x8*)(Ks + tl * 64 + (((4 + quad) ^ (tl & 7)) * 8));
            f32x4 s = (f32x4){0.f, 0.f, 0.f, 0.f};
            s = __builtin_amdgcn_mfma_f32_16x16x32_bf16(a0, qf[0], s, 0, 0, 0);
            s = __builtin_amdgcn_mfma_f32_16x16x32_bf16(a1, qf[1], s, 0, 0, 0);
            st[tg] = s;
        }
        __builtin_amdgcn_s_setprio(0);

        unsigned long long s0 = mw.x >> (quad * 4);
        unsigned long long s1 = mw.y >> (quad * 4);
        bf16x8 pva[4];
#pragma unroll
        for (int tg = 0; tg < 8; ++tg) {
            unsigned int bits = (unsigned int)(((tg < 4) ? s0 : s1) >> ((tg & 3) * 16));
#pragma unroll
            for (int r = 0; r < 4; ++r) {
                float p = __builtin_amdgcn_exp2f(st[tg][r]);
                p = ((bits >> r) & 1u) ? 0.f : p;
                pva[tg >> 1][(tg & 1) * 4 + r] = (bf16)p;
            }
        }

        __builtin_amdgcn_s_setprio(1);
#pragma unroll
        for (int kc = 0; kc < 4; ++kc) {
#pragma unroll
            for (int dg = 0; dg < 4; ++dg) {
                bf16x8 bfrag = *(const bf16x8*)(Vts + (dg * 16 + l16) * 136 + kc * 32 + quad * 8);
                oacc[dg] = __builtin_amdgcn_mfma_f32_16x16x32_bf16(pva[kc], bfrag, oacc[dg], 0, 0, 0);
            }
            lacc = __builtin_amdgcn_mfma_f32_16x16x32_bf16(pva[kc], ones, lacc, 0, 0, 0);
        }
        __builtin_amdgcn_s_setprio(0);
    }

#pragma unroll
    for (int r = 0; r < 4; ++r) {
        float inv_l = 1.f / lacc[r];
        bf16* orow = o + (rowb + q0 + wave * 16 + quad * 4 + r) * DD + h * 64;
#pragma unroll
        for (int dg = 0; dg < 4; ++dg)
            orow[dg * 16 + l16] = (bf16)(oacc[dg][r] * inv_l);
    }
}

// ---------------- fused split-K reduce + bias (+gelu) + residual LayerNorm ----------------
template <bool GELU, bool WB16, int NP>
__global__ __launch_bounds__(256) void ln_fused(const float* __restrict__ resid,
                                                const float* __restrict__ p0,
                                                const float* __restrict__ p1,
                                                const float* __restrict__ p2,
                                                const float* __restrict__ p3,
                                                const float* __restrict__ bias,
                                                const float* __restrict__ g,
                                                const float* __restrict__ bb,
                                                float* __restrict__ outf,
                                                bf16* __restrict__ outb) {
    const int row = blockIdx.x;
    const int tid = threadIdx.x;
    const size_t base = (size_t)row * DD + tid * 4;
    float4 a0 = *(const float4*)(p0 + base);
    float4 a1 = *(const float4*)(p1 + base);
    float4 bz = *(const float4*)(bias + tid * 4);
    float ax = a0.x + a1.x + bz.x;
    float ay = a0.y + a1.y + bz.y;
    float az = a0.z + a1.z + bz.z;
    float aw = a0.w + a1.w + bz.w;
    if (NP == 4) {
        float4 a2 = *(const float4*)(p2 + base);
        float4 a3 = *(const float4*)(p3 + base);
        ax += a2.x + a3.x; ay += a2.y + a3.y; az += a2.z + a3.z; aw += a2.w + a3.w;
    }
    if (GELU) { ax = gelu_exact(ax); ay = gelu_exact(ay); az = gelu_exact(az); aw = gelu_exact(aw); }
    float s1 = ax + ay + az + aw;
    float s2 = ax * ax + ay * ay + az * az + aw * aw;
#pragma unroll
    for (int off = 32; off; off >>= 1) {
        s1 += __shfl_xor(s1, off, 64);
        s2 += __shfl_xor(s2, off, 64);
    }
    __shared__ float red[8];
    if ((tid & 63) == 0) { red[(tid >> 6) * 2] = s1; red[(tid >> 6) * 2 + 1] = s2; }
    __syncthreads();
    s1 = red[0] + red[2] + red[4] + red[6];
    s2 = red[1] + red[3] + red[5] + red[7];
    float mean = s1 * (1.f / DD);
    float var  = s2 * (1.f / DD) - mean * mean;
    float rs = rsqrtf(var + 1e-5f);
    float4 gv = *(const float4*)(g + tid * 4);
    float4 bv = *(const float4*)(bb + tid * 4);
    float4 rv = *(const float4*)(resid + base);
    float y0 = rv.x + (ax - mean) * rs * gv.x + bv.x;
    float y1 = rv.y + (ay - mean) * rs * gv.y + bv.y;
    float y2 = rv.z + (az - mean) * rs * gv.z + bv.z;
    float y3 = rv.w + (aw - mean) * rs * gv.w + bv.w;
    float4 yo = make_float4(y0, y1, y2, y3);
    *(float4*)(outf + base) = yo;
    if (WB16) {
        bf16x4 ob;
        ob[0] = (bf16)y0; ob[1] = (bf16)y1; ob[2] = (bf16)y2; ob[3] = (bf16)y3;
        *(bf16x4*)(outb + base) = ob;
    }
}

// ---------------- launcher ----------------
extern "C" void kernel_launch(void* const* d_in, const int* in_sizes, int n_in,
                              void* d_out, int out_size, void* d_ws, size_t ws_size,
                              hipStream_t stream) {
    const float* x    = (const float*)d_in[0];
    const int*   mask = (const int*)d_in[1];
    const float* Wq   = (const float*)d_in[2];
    const float* Wk   = (const float*)d_in[3];
    const float* Wv   = (const float*)d_in[4];
    const float* Wo   = (const float*)d_in[5];
    const float* bo   = (const float*)d_in[6];
    const float* ln1g = (const float*)d_in[7];
    const float* ln1b = (const float*)d_in[8];
    const float* W1   = (const float*)d_in[9];
    const float* b1   = (const float*)d_in[10];
    const float* W2   = (const float*)d_in[11];
    const float* b2   = (const float*)d_in[12];
    const float* ln2g = (const float*)d_in[13];
    const float* ln2b = (const float*)d_in[14];

    char* w = (char*)d_ws;
    bf16* Wqkv_t = (bf16*)w; w += (size_t)3072 * 1024 * 2;   // 6 MB
    bf16* Wo_t   = (bf16*)w; w += (size_t)1024 * 1024 * 2;   // 2 MB
    bf16* W1_t   = (bf16*)w; w += (size_t)4096 * 1024 * 2;   // 8 MB
    bf16* W2_t   = (bf16*)w; w += (size_t)1024 * 4096 * 2;   // 8 MB
    bf16* x_b    = (bf16*)w; w += (size_t)MROWS * DD * 2;    // 8 MB (then o_b, x1_b, FFN2 fp1)
    bf16* qkv    = (bf16*)w; w += (size_t)MROWS * 3072 * 2;  // 24 MB (then FFN2 fp1 tail / fp2)
    float* R     = (float*)w; w += (size_t)MROWS * DD * 8;   // 32 MB (O-proj p0/p1, then h_b)
    float* x1_f  = (float*)w; w += (size_t)MROWS * DD * 4;   // 16 MB
    unsigned long long* maskb = (unsigned long long*)w; w += (size_t)SS * 32 * 8;  // 0.5 MB
    bf16* o_b  = x_b;                 // alive: attention -> O-proj
    bf16* x1_b = x_b;                 // alive: LN1 -> FFN1
    float* op0 = R;                   // O-proj partial z=0
    float* op1 = R + (size_t)MROWS * DD;  // O-proj partial z=1
    bf16*  h_b = (bf16*)R;            // FFN1 out (32 MB; partials dead by then)
    // FFN2 split-4 fp32 partials (16 MB each), all regions dead by FFN2 time:
    float* fp0 = (float*)d_out;                            // reduced in-place by LN2
    float* fp1 = (float*)x_b;                              // x_b (8 MB) + qkv head (8 MB)
    float* fp2 = (float*)x_b + (size_t)4 * 1024 * 1024;    // qkv tail (16 MB)
    float* fp3 = (float*)d_ws;                             // Wqkv_t+Wo_t+W1_t (16 MB, dead after FFN1)

    // fused prep (one launch)
    prep_kernel<<<32768, 256, 0, stream>>>(x, x_b, mask, maskb,
                                           Wq, Wk, Wv, Wo, W1, W2,
                                           Wqkv_t, Wo_t, W1_t, W2_t);

    // QKV projection: [4096,1024] x [1024,3072] -> qkv bf16  (256^2 counted-vmcnt)
    gemm256<0><<<dim3(12, 16, 1), 512, 0, stream>>>(x_b, Wqkv_t, qkv, nullptr, nullptr, nullptr, nullptr, MROWS, 3072, 1024, 1024);
    // attention (512-thread blocks, 128 q-rows each)
    flash_attn<<<dim3(SS / 128, BB * HH), 512, 0, stream>>>(qkv, maskb, o_b);
    // O-proj, split-K=2 -> fp32 partials (bias deferred to LN1)
    gemm_bt<4><<<dim3(8, 32, 2), 256, 0, stream>>>(o_b, Wo_t, op0, op1, nullptr, MROWS, 1024, 512, 1024);
    // x1 = x + LN(op0+op1+bo)
    ln_fused<false, true, 2><<<MROWS, 256, 0, stream>>>(x, op0, op1, nullptr, nullptr, bo, ln1g, ln1b, x1_f, x1_b);
    // FFN1: gelu(x1@W1 + b1) -> bf16  (256^2 counted-vmcnt)
    gemm256<2><<<dim3(16, 16, 1), 512, 0, stream>>>(x1_b, W1_t, h_b, nullptr, nullptr, nullptr, b1, MROWS, 4096, 1024, 1024);
    // FFN2, split-K=4 -> fp32 partials (bias+gelu deferred to LN2)  (256^2 counted-vmcnt)
    gemm256<4><<<dim3(4, 16, 4), 512, 0, stream>>>(h_b, W2_t, fp0, fp1, fp2, fp3, nullptr, MROWS, 1024, 1024, 4096);
    // out = x1 + LN(gelu(fp0+fp1+fp2+fp3+b2))  (fp32, in-place on d_out)
    ln_fused<true, false, 4><<<MROWS, 256, 0, stream>>>(x1_f, fp0, fp1, fp2, fp3, b2, ln2g, ln2b, (float*)d_out, nullptr);
}